// Round 13
// baseline (126.566 us; speedup 1.0000x reference)
//
#include <hip/hip_runtime.h>
#include <hip/hip_bf16.h>

#define F 64
#define SLOPE 0.2f
#define NB_SHIFT 7     // 128 nodes per coarse bucket
#define BMASK 127
#define NBMAX 1024
#define BATCH 4096     // edges per gat_bin block
#define HIST_BLOCKS 128
#define MAXE 6144      // max edges per bucket in LDS (mean ~2046, sigma ~45)

__device__ inline unsigned short f2bf(float f) {
    unsigned u = __float_as_uint(f);
    unsigned r = (u + 0x7FFFu + ((u >> 16) & 1u)) >> 16;
    return (unsigned short)r;
}

// ---------------- Kernel 1: h(bf16) = X @ W + fused s1/s2 -------------------
__global__ __launch_bounds__(256) void gat_gemm(
    const float* __restrict__ X, const float* __restrict__ W,
    const float* __restrict__ a, unsigned short* __restrict__ hb,
    float* __restrict__ s1, float* __restrict__ s2, int N) {
    __shared__ __align__(16) char smem[51200];
    float* XsT = (float*)smem;              // 64*132*4 = 33792 B
    float* Wsm = (float*)(smem + 33792);    // 64*68*4  = 17408 B

    const int tid = threadIdx.x;
    const int base = blockIdx.x * 128;

#pragma unroll
    for (int l = 0; l < 8; ++l) {
        int flat = l * 256 + tid;
        int rr = flat >> 4;
        int qc = flat & 15;
        float4 v = make_float4(0.f, 0.f, 0.f, 0.f);
        if (base + rr < N) v = *(const float4*)&X[(size_t)(base + rr) * F + qc * 4];
        XsT[(qc * 4 + 0) * 132 + rr] = v.x;
        XsT[(qc * 4 + 1) * 132 + rr] = v.y;
        XsT[(qc * 4 + 2) * 132 + rr] = v.z;
        XsT[(qc * 4 + 3) * 132 + rr] = v.w;
    }
#pragma unroll
    for (int l = 0; l < 4; ++l) {
        int flat = l * 256 + tid;
        int k = flat >> 4;
        int qc = flat & 15;
        float4 v = *(const float4*)&W[k * F + qc * 4];
        *(float4*)&Wsm[k * 68 + qc * 4] = v;
    }
    __syncthreads();

    const int r0 = (tid >> 4) * 8;
    const int c0 = (tid & 15) * 4;

    float4 acc[8];
#pragma unroll
    for (int i = 0; i < 8; ++i) acc[i] = make_float4(0.f, 0.f, 0.f, 0.f);

#pragma unroll 8
    for (int k = 0; k < F; ++k) {
        float4 xa = *(float4*)&XsT[k * 132 + r0];
        float4 xb = *(float4*)&XsT[k * 132 + r0 + 4];
        float4 wv = *(float4*)&Wsm[k * 68 + c0];
        float xs[8] = {xa.x, xa.y, xa.z, xa.w, xb.x, xb.y, xb.z, xb.w};
#pragma unroll
        for (int i = 0; i < 8; ++i) {
            acc[i].x = fmaf(xs[i], wv.x, acc[i].x);
            acc[i].y = fmaf(xs[i], wv.y, acc[i].y);
            acc[i].z = fmaf(xs[i], wv.z, acc[i].z);
            acc[i].w = fmaf(xs[i], wv.w, acc[i].w);
        }
    }

#pragma unroll
    for (int i = 0; i < 8; ++i) {
        int r = base + r0 + i;
        if (r < N) {
            ushort4 hv;
            hv.x = f2bf(acc[i].x);
            hv.y = f2bf(acc[i].y);
            hv.z = f2bf(acc[i].z);
            hv.w = f2bf(acc[i].w);
            *(ushort4*)&hb[(size_t)r * F + c0] = hv;
        }
    }

    float4 a1 = *(const float4*)&a[c0];
    float4 a2 = *(const float4*)&a[F + c0];
    __syncthreads();
    float2* red = (float2*)Wsm;            // [16][128] float2
    const int cg = tid & 15;
#pragma unroll
    for (int i = 0; i < 8; ++i) {
        float p = acc[i].x * a1.x + acc[i].y * a1.y + acc[i].z * a1.z + acc[i].w * a1.w;
        float q = acc[i].x * a2.x + acc[i].y * a2.y + acc[i].z * a2.z + acc[i].w * a2.w;
        red[cg * 128 + r0 + i] = make_float2(p, q);
    }
    __syncthreads();
    if (tid < 128) {
        float p = 0.f, q = 0.f;
#pragma unroll
        for (int g = 0; g < 16; ++g) {
            float2 t = red[g * 128 + tid];
            p += t.x;
            q += t.y;
        }
        int r = base + tid;
        if (r < N) {
            s1[r] = p;
            s2[r] = q;
        }
    }
}

// ---------------- Kernel 2: bucket histogram, per-block partials ------------
__global__ __launch_bounds__(256) void gat_histb(
    const int* __restrict__ src, int* __restrict__ partialHist, int E) {
    __shared__ int lh[NBMAX];
    int tid = threadIdx.x;
    for (int i = tid; i < NBMAX; i += 256) lh[i] = 0;
    __syncthreads();
    for (int i = blockIdx.x * 256 + tid; i < E; i += HIST_BLOCKS * 256)
        atomicAdd(&lh[src[i] >> NB_SHIFT], 1);
    __syncthreads();
    for (int i = tid; i < NBMAX; i += 256)
        partialHist[blockIdx.x * NBMAX + i] = lh[i];
}

// ---------------- Kernel 3: sum partials + pairwise scan --------------------
__global__ __launch_bounds__(512) void gat_scan0(
    const int* __restrict__ partialHist, int* __restrict__ bucketBase,
    int* __restrict__ bucketCursor, int NB) {
    __shared__ int wsum[8];
    int tid = threadIdx.x, lane = tid & 63, wid = tid >> 6;
    int i0 = 2 * tid, i1 = 2 * tid + 1;
    int v0 = 0, v1 = 0;
    for (int p = 0; p < HIST_BLOCKS; ++p) {
        v0 += partialHist[p * NBMAX + i0];
        v1 += partialHist[p * NBMAX + i1];
    }
    int pv = v0 + v1;
    int x = pv;
#pragma unroll
    for (int off = 1; off < 64; off <<= 1) {
        int y = __shfl_up(x, off, 64);
        if (lane >= off) x += y;
    }
    if (lane == 63) wsum[wid] = x;
    __syncthreads();
    int add = 0;
    for (int w = 0; w < 8; ++w)
        if (w < wid) add += wsum[w];
    int ex = add + x - pv;
    if (i0 < NB) {
        bucketBase[i0] = ex;
        bucketCursor[i0] = ex;
    }
    if (i1 < NB) {
        bucketBase[i1] = ex + v0;
        bucketCursor[i1] = ex + v0;
    }
    if (i0 == NB - 1) bucketBase[NB] = ex + v0;
    if (i1 == NB - 1) bucketBase[NB] = ex + v0 + v1;
}

// ---------------- Kernel 4: coarse radix partition by src>>7, packed out ----
// bucketData element: (src & 127) << 24 | dst   (dst < 2^24)
__global__ __launch_bounds__(512) void gat_bin(
    const int* __restrict__ src, const int* __restrict__ dst,
    int* __restrict__ bucketCursor, unsigned* __restrict__ bucketData, int E) {
    __shared__ int hist[NBMAX], excl[NBMAX], gbase[NBMAX], cur[NBMAX];
    __shared__ int wsum[8];
    __shared__ int2 staged[BATCH];
    int tid = threadIdx.x, lane = tid & 63, wid = tid >> 6;
    int base = blockIdx.x * BATCH;
    int n = E - base;
    if (n > BATCH) n = BATCH;

    hist[tid] = 0;
    hist[tid + 512] = 0;
    __syncthreads();

    int se[8], de[8];
#pragma unroll
    for (int j = 0; j < 8; ++j) {
        int i = base + j * 512 + tid;
        se[j] = -1;
        de[j] = 0;
        if (i < E) {
            se[j] = src[i];
            de[j] = dst[i];
            atomicAdd(&hist[se[j] >> NB_SHIFT], 1);
        }
    }
    __syncthreads();
    // pairwise wave-shuffle exclusive scan of hist[1024]
    int v0 = hist[2 * tid], v1 = hist[2 * tid + 1];
    int pv = v0 + v1;
    int x = pv;
#pragma unroll
    for (int off = 1; off < 64; off <<= 1) {
        int y = __shfl_up(x, off, 64);
        if (lane >= off) x += y;
    }
    if (lane == 63) wsum[wid] = x;
    __syncthreads();
    int add = 0;
    for (int w = 0; w < 8; ++w)
        if (w < wid) add += wsum[w];
    int ex = add + x - pv;
    excl[2 * tid] = ex;
    excl[2 * tid + 1] = ex + v0;
    cur[2 * tid] = ex;
    cur[2 * tid + 1] = ex + v0;
    __syncthreads();
#pragma unroll
    for (int j = 0; j < 8; ++j) {
        if (se[j] >= 0) {
            int b = se[j] >> NB_SHIFT;
            int pos = atomicAdd(&cur[b], 1);
            staged[pos] = make_int2(se[j], de[j]);
        }
    }
    if (v0 > 0) gbase[2 * tid] = atomicAdd(&bucketCursor[2 * tid], v0);
    if (v1 > 0) gbase[2 * tid + 1] = atomicAdd(&bucketCursor[2 * tid + 1], v1);
    __syncthreads();
    for (int i = tid; i < n; i += 512) {
        int2 p = staged[i];
        int b = p.x >> NB_SHIFT;
        bucketData[gbase[b] + (i - excl[b])] =
            ((unsigned)(p.x & BMASK) << 24) | (unsigned)p.y;
    }
}

// ---------------- Kernel 5: fused bucket CSR (in LDS) + aggregate -----------
// One block per 128-node bucket. Phase 1: build local CSR in LDS. Phase 2:
// 8-lane subgroup per node, 4 nodes per subgroup, edge lists read from LDS.
__global__ __launch_bounds__(256) void gat_bucket_agg(
    const int* __restrict__ bucketBase, const unsigned* __restrict__ bucketData,
    const float* __restrict__ s1, const float* __restrict__ s2,
    const unsigned short* __restrict__ hb, float* __restrict__ out, int N) {
    __shared__ int cnt[128], cur[128], rptr[129];
    __shared__ int wsum[4];
    __shared__ int sortedDstL[MAXE];

    const int b = blockIdx.x;
    const int tid = threadIdx.x, lane = tid & 63, wid = tid >> 6;
    const int node0 = b << NB_SHIFT;
    const int beg = bucketBase[b];
    const int end = bucketBase[b + 1];
    const int n = end - beg;

    const int fo = (tid & 7) * 8;    // feature octet owned by this lane
    const int sgId = tid >> 3;       // 0..31

    if (n <= MAXE) {
        // --- phase 1: LDS CSR ---
        if (tid < 128) cnt[tid] = 0;
        __syncthreads();
        for (int i = beg + tid; i < end; i += 256)
            atomicAdd(&cnt[bucketData[i] >> 24], 1);
        __syncthreads();
        int v = (tid < 128) ? cnt[tid] : 0;
        int x = v;
#pragma unroll
        for (int off = 1; off < 64; off <<= 1) {
            int y = __shfl_up(x, off, 64);
            if (lane >= off) x += y;
        }
        if (lane == 63) wsum[wid] = x;
        __syncthreads();
        int add = 0;
        for (int w = 0; w < 4; ++w)
            if (w < wid) add += wsum[w];
        int excl = add + x - v;
        if (tid < 128) {
            rptr[tid] = excl;
            cur[tid] = excl;
        }
        if (tid == 127) rptr[128] = excl + v;
        __syncthreads();
        for (int i = beg + tid; i < end; i += 256) {
            unsigned w = bucketData[i];
            int pos = atomicAdd(&cur[w >> 24], 1);
            sortedDstL[pos] = (int)(w & 0xFFFFFFu);
        }
        __syncthreads();

        // --- phase 2: aggregate from LDS lists ---
#pragma unroll
        for (int it = 0; it < 4; ++it) {
            int r = sgId * 4 + it;
            int node = node0 + r;
            if (node >= N) continue;
            int eb = rptr[r], ee = rptr[r + 1];
            float s1s = s1[node];
            float as = s1s + s2[node];
            as = (as >= 0.f) ? as : SLOPE * as;
            as = expf(as);

            float accA[8], accB[8];
            {
                uint4 hv = *(const uint4*)&hb[(size_t)node * F + fo];
                accA[0] = as * __uint_as_float(hv.x << 16);
                accA[1] = as * __uint_as_float(hv.x & 0xFFFF0000u);
                accA[2] = as * __uint_as_float(hv.y << 16);
                accA[3] = as * __uint_as_float(hv.y & 0xFFFF0000u);
                accA[4] = as * __uint_as_float(hv.z << 16);
                accA[5] = as * __uint_as_float(hv.z & 0xFFFF0000u);
                accA[6] = as * __uint_as_float(hv.w << 16);
                accA[7] = as * __uint_as_float(hv.w & 0xFFFF0000u);
            }
#pragma unroll
            for (int i = 0; i < 8; ++i) accB[i] = 0.f;

            float dsum = as;
            int e = eb;
            for (; e + 2 <= ee; e += 2) {
                int d0 = sortedDstL[e];
                int d1 = sortedDstL[e + 1];
                float t0 = s1s + s2[d0];
                float t1 = s1s + s2[d1];
                t0 = (t0 >= 0.f) ? t0 : SLOPE * t0;
                t1 = (t1 >= 0.f) ? t1 : SLOPE * t1;
                float a0 = expf(t0);
                float a1 = expf(t1);
                dsum += a0 + a1;
                uint4 g0 = *(const uint4*)&hb[(size_t)d0 * F + fo];
                uint4 g1 = *(const uint4*)&hb[(size_t)d1 * F + fo];
                accA[0] = fmaf(a0, __uint_as_float(g0.x << 16), accA[0]);
                accA[1] = fmaf(a0, __uint_as_float(g0.x & 0xFFFF0000u), accA[1]);
                accA[2] = fmaf(a0, __uint_as_float(g0.y << 16), accA[2]);
                accA[3] = fmaf(a0, __uint_as_float(g0.y & 0xFFFF0000u), accA[3]);
                accA[4] = fmaf(a0, __uint_as_float(g0.z << 16), accA[4]);
                accA[5] = fmaf(a0, __uint_as_float(g0.z & 0xFFFF0000u), accA[5]);
                accA[6] = fmaf(a0, __uint_as_float(g0.w << 16), accA[6]);
                accA[7] = fmaf(a0, __uint_as_float(g0.w & 0xFFFF0000u), accA[7]);
                accB[0] = fmaf(a1, __uint_as_float(g1.x << 16), accB[0]);
                accB[1] = fmaf(a1, __uint_as_float(g1.x & 0xFFFF0000u), accB[1]);
                accB[2] = fmaf(a1, __uint_as_float(g1.y << 16), accB[2]);
                accB[3] = fmaf(a1, __uint_as_float(g1.y & 0xFFFF0000u), accB[3]);
                accB[4] = fmaf(a1, __uint_as_float(g1.z << 16), accB[4]);
                accB[5] = fmaf(a1, __uint_as_float(g1.z & 0xFFFF0000u), accB[5]);
                accB[6] = fmaf(a1, __uint_as_float(g1.w << 16), accB[6]);
                accB[7] = fmaf(a1, __uint_as_float(g1.w & 0xFFFF0000u), accB[7]);
            }
            if (e < ee) {
                int d0 = sortedDstL[e];
                float t0 = s1s + s2[d0];
                t0 = (t0 >= 0.f) ? t0 : SLOPE * t0;
                float a0 = expf(t0);
                dsum += a0;
                uint4 g0 = *(const uint4*)&hb[(size_t)d0 * F + fo];
                accA[0] = fmaf(a0, __uint_as_float(g0.x << 16), accA[0]);
                accA[1] = fmaf(a0, __uint_as_float(g0.x & 0xFFFF0000u), accA[1]);
                accA[2] = fmaf(a0, __uint_as_float(g0.y << 16), accA[2]);
                accA[3] = fmaf(a0, __uint_as_float(g0.y & 0xFFFF0000u), accA[3]);
                accA[4] = fmaf(a0, __uint_as_float(g0.z << 16), accA[4]);
                accA[5] = fmaf(a0, __uint_as_float(g0.z & 0xFFFF0000u), accA[5]);
                accA[6] = fmaf(a0, __uint_as_float(g0.w << 16), accA[6]);
                accA[7] = fmaf(a0, __uint_as_float(g0.w & 0xFFFF0000u), accA[7]);
            }

            float inv = 1.0f / dsum;
            float4 r0v, r1v;
            r0v.x = (accA[0] + accB[0]) * inv;
            r0v.y = (accA[1] + accB[1]) * inv;
            r0v.z = (accA[2] + accB[2]) * inv;
            r0v.w = (accA[3] + accB[3]) * inv;
            r1v.x = (accA[4] + accB[4]) * inv;
            r1v.y = (accA[5] + accB[5]) * inv;
            r1v.z = (accA[6] + accB[6]) * inv;
            r1v.w = (accA[7] + accB[7]) * inv;
            *(float4*)&out[(size_t)node * F + fo] = r0v;
            *(float4*)&out[(size_t)node * F + fo + 4] = r1v;
        }
    } else {
        // --- slow fallback (statistically unreachable): scan whole bucket ---
        for (int it = 0; it < 4; ++it) {
            int r = sgId * 4 + it;
            int node = node0 + r;
            if (node >= N) continue;
            float s1s = s1[node];
            float as = s1s + s2[node];
            as = (as >= 0.f) ? as : SLOPE * as;
            as = expf(as);
            float acc[8];
            {
                uint4 hv = *(const uint4*)&hb[(size_t)node * F + fo];
                acc[0] = as * __uint_as_float(hv.x << 16);
                acc[1] = as * __uint_as_float(hv.x & 0xFFFF0000u);
                acc[2] = as * __uint_as_float(hv.y << 16);
                acc[3] = as * __uint_as_float(hv.y & 0xFFFF0000u);
                acc[4] = as * __uint_as_float(hv.z << 16);
                acc[5] = as * __uint_as_float(hv.z & 0xFFFF0000u);
                acc[6] = as * __uint_as_float(hv.w << 16);
                acc[7] = as * __uint_as_float(hv.w & 0xFFFF0000u);
            }
            float dsum = as;
            for (int i = beg; i < end; ++i) {
                unsigned w = bucketData[i];
                if ((int)(w >> 24) != r) continue;
                int d0 = (int)(w & 0xFFFFFFu);
                float t0 = s1s + s2[d0];
                t0 = (t0 >= 0.f) ? t0 : SLOPE * t0;
                float a0 = expf(t0);
                dsum += a0;
                uint4 g0 = *(const uint4*)&hb[(size_t)d0 * F + fo];
                acc[0] = fmaf(a0, __uint_as_float(g0.x << 16), acc[0]);
                acc[1] = fmaf(a0, __uint_as_float(g0.x & 0xFFFF0000u), acc[1]);
                acc[2] = fmaf(a0, __uint_as_float(g0.y << 16), acc[2]);
                acc[3] = fmaf(a0, __uint_as_float(g0.y & 0xFFFF0000u), acc[3]);
                acc[4] = fmaf(a0, __uint_as_float(g0.z << 16), acc[4]);
                acc[5] = fmaf(a0, __uint_as_float(g0.z & 0xFFFF0000u), acc[5]);
                acc[6] = fmaf(a0, __uint_as_float(g0.w << 16), acc[6]);
                acc[7] = fmaf(a0, __uint_as_float(g0.w & 0xFFFF0000u), acc[7]);
            }
            float inv = 1.0f / dsum;
            float4 r0v = make_float4(acc[0] * inv, acc[1] * inv, acc[2] * inv, acc[3] * inv);
            float4 r1v = make_float4(acc[4] * inv, acc[5] * inv, acc[6] * inv, acc[7] * inv);
            *(float4*)&out[(size_t)node * F + fo] = r0v;
            *(float4*)&out[(size_t)node * F + fo + 4] = r1v;
        }
    }
}

extern "C" void kernel_launch(void* const* d_in, const int* in_sizes, int n_in,
                              void* d_out, int out_size, void* d_ws, size_t ws_size,
                              hipStream_t stream) {
    const float* X = (const float*)d_in[0];
    const int* edge = (const int*)d_in[1];
    const float* W = (const float*)d_in[2];
    const float* a = (const float*)d_in[3];

    int N = in_sizes[0] / F;
    int E = in_sizes[1] / 2;
    int NB = (N + BMASK) >> NB_SHIFT;  // 128-node buckets (<= 1024)

    const int* src = edge;
    const int* dst = edge + E;

    // ws: bucketData[E]u32 | hb[N*64]u16 | s1[N] | s2[N] |
    //     partialHist[128*1024] | bucketBase[1025] | bucketCursor[1024]
    unsigned* bucketData = (unsigned*)d_ws;
    unsigned short* hb = (unsigned short*)(bucketData + E);
    float* s1 = (float*)(hb + (size_t)N * F);
    float* s2 = s1 + N;
    int* partialHist = (int*)(s2 + N);
    int* bucketBase = partialHist + HIST_BLOCKS * NBMAX;
    int* bucketCursor = bucketBase + (NBMAX + 1);

    float* out = (float*)d_out;

    int gemmBlocks = (N + 127) / 128;
    gat_gemm<<<gemmBlocks, 256, 0, stream>>>(X, W, a, hb, s1, s2, N);

    gat_histb<<<HIST_BLOCKS, 256, 0, stream>>>(src, partialHist, E);

    gat_scan0<<<1, 512, 0, stream>>>(partialHist, bucketBase, bucketCursor, NB);

    int binBlocks = (E + BATCH - 1) / BATCH;
    gat_bin<<<binBlocks, 512, 0, stream>>>(src, dst, bucketCursor, bucketData, E);

    gat_bucket_agg<<<NB, 256, 0, stream>>>(bucketBase, bucketData, s1, s2, hb,
                                           out, N);
}

// Round 14
// 116.689 us; speedup vs baseline: 1.0846x; 1.0846x over previous
//
#include <hip/hip_runtime.h>
#include <hip/hip_bf16.h>

#define F 64
#define SLOPE 0.2f
#define NB_SHIFT 8     // 256 nodes per coarse bucket
#define BATCH 4096     // edges per gat_bin block
#define HIST_BLOCKS 128

__device__ inline unsigned short f2bf(float f) {
    unsigned u = __float_as_uint(f);
    unsigned r = (u + 0x7FFFu + ((u >> 16) & 1u)) >> 16;
    return (unsigned short)r;
}

// ---------------- Kernel 1: h(bf16) = X @ W + fused s1/s2 -------------------
__global__ __launch_bounds__(256) void gat_gemm(
    const float* __restrict__ X, const float* __restrict__ W,
    const float* __restrict__ a, unsigned short* __restrict__ hb,
    float* __restrict__ s1, float* __restrict__ s2, int N) {
    __shared__ __align__(16) char smem[51200];
    float* XsT = (float*)smem;              // 64*132*4 = 33792 B
    float* Wsm = (float*)(smem + 33792);    // 64*68*4  = 17408 B

    const int tid = threadIdx.x;
    const int base = blockIdx.x * 128;

#pragma unroll
    for (int l = 0; l < 8; ++l) {
        int flat = l * 256 + tid;
        int rr = flat >> 4;
        int qc = flat & 15;
        float4 v = make_float4(0.f, 0.f, 0.f, 0.f);
        if (base + rr < N) v = *(const float4*)&X[(size_t)(base + rr) * F + qc * 4];
        XsT[(qc * 4 + 0) * 132 + rr] = v.x;
        XsT[(qc * 4 + 1) * 132 + rr] = v.y;
        XsT[(qc * 4 + 2) * 132 + rr] = v.z;
        XsT[(qc * 4 + 3) * 132 + rr] = v.w;
    }
#pragma unroll
    for (int l = 0; l < 4; ++l) {
        int flat = l * 256 + tid;
        int k = flat >> 4;
        int qc = flat & 15;
        float4 v = *(const float4*)&W[k * F + qc * 4];
        *(float4*)&Wsm[k * 68 + qc * 4] = v;
    }
    __syncthreads();

    const int r0 = (tid >> 4) * 8;
    const int c0 = (tid & 15) * 4;

    float4 acc[8];
#pragma unroll
    for (int i = 0; i < 8; ++i) acc[i] = make_float4(0.f, 0.f, 0.f, 0.f);

#pragma unroll 8
    for (int k = 0; k < F; ++k) {
        float4 xa = *(float4*)&XsT[k * 132 + r0];
        float4 xb = *(float4*)&XsT[k * 132 + r0 + 4];
        float4 wv = *(float4*)&Wsm[k * 68 + c0];
        float xs[8] = {xa.x, xa.y, xa.z, xa.w, xb.x, xb.y, xb.z, xb.w};
#pragma unroll
        for (int i = 0; i < 8; ++i) {
            acc[i].x = fmaf(xs[i], wv.x, acc[i].x);
            acc[i].y = fmaf(xs[i], wv.y, acc[i].y);
            acc[i].z = fmaf(xs[i], wv.z, acc[i].z);
            acc[i].w = fmaf(xs[i], wv.w, acc[i].w);
        }
    }

#pragma unroll
    for (int i = 0; i < 8; ++i) {
        int r = base + r0 + i;
        if (r < N) {
            ushort4 hv;
            hv.x = f2bf(acc[i].x);
            hv.y = f2bf(acc[i].y);
            hv.z = f2bf(acc[i].z);
            hv.w = f2bf(acc[i].w);
            *(ushort4*)&hb[(size_t)r * F + c0] = hv;
        }
    }

    float4 a1 = *(const float4*)&a[c0];
    float4 a2 = *(const float4*)&a[F + c0];
    __syncthreads();
    float2* red = (float2*)Wsm;            // [16][128] float2
    const int cg = tid & 15;
#pragma unroll
    for (int i = 0; i < 8; ++i) {
        float p = acc[i].x * a1.x + acc[i].y * a1.y + acc[i].z * a1.z + acc[i].w * a1.w;
        float q = acc[i].x * a2.x + acc[i].y * a2.y + acc[i].z * a2.z + acc[i].w * a2.w;
        red[cg * 128 + r0 + i] = make_float2(p, q);
    }
    __syncthreads();
    if (tid < 128) {
        float p = 0.f, q = 0.f;
#pragma unroll
        for (int g = 0; g < 16; ++g) {
            float2 t = red[g * 128 + tid];
            p += t.x;
            q += t.y;
        }
        int r = base + tid;
        if (r < N) {
            s1[r] = p;
            s2[r] = q;
        }
    }
}

// ---------------- Kernel 2: bucket histogram, per-block partials ------------
__global__ __launch_bounds__(256) void gat_histb(
    const int* __restrict__ src, int* __restrict__ partialHist, int E) {
    __shared__ int lh[512];
    int tid = threadIdx.x;
    for (int i = tid; i < 512; i += 256) lh[i] = 0;
    __syncthreads();
    for (int i = blockIdx.x * 256 + tid; i < E; i += HIST_BLOCKS * 256)
        atomicAdd(&lh[src[i] >> NB_SHIFT], 1);
    __syncthreads();
    for (int i = tid; i < 512; i += 256)
        partialHist[blockIdx.x * 512 + i] = lh[i];
}

// ---------------- Kernel 3: sum partials + scan -> bucketBase/Cursor --------
__global__ __launch_bounds__(512) void gat_scan0(
    const int* __restrict__ partialHist, int* __restrict__ bucketBase,
    int* __restrict__ bucketCursor, int* __restrict__ rowptrN, int NB) {
    __shared__ int wsum[8];
    int tid = threadIdx.x, lane = tid & 63, wid = tid >> 6;
    int v = 0;
    for (int p = 0; p < HIST_BLOCKS; ++p)
        v += partialHist[p * 512 + tid];
    int x = v;
#pragma unroll
    for (int off = 1; off < 64; off <<= 1) {
        int y = __shfl_up(x, off, 64);
        if (lane >= off) x += y;
    }
    if (lane == 63) wsum[wid] = x;
    __syncthreads();
    int add = 0;
    for (int w = 0; w < 8; ++w)
        if (w < wid) add += wsum[w];
    int excl = add + x - v;
    if (tid < NB) {
        bucketBase[tid] = excl;
        bucketCursor[tid] = excl;
    }
    if (tid == NB - 1) {
        bucketBase[NB] = excl + v;   // == E
        rowptrN[0] = excl + v;       // rowptr[N] = E
    }
}

// ---------------- Kernel 4: coarse radix partition by src>>8, packed out ----
// bucketData element: (src & 255) << 24 | dst   (dst < 2^24)
__global__ __launch_bounds__(512) void gat_bin(
    const int* __restrict__ src, const int* __restrict__ dst,
    int* __restrict__ bucketCursor, unsigned* __restrict__ bucketData, int E) {
    __shared__ int hist[512], excl[512], gbase[512], cur[512];
    __shared__ int wsum[8];
    __shared__ int2 staged[BATCH];
    int tid = threadIdx.x, lane = tid & 63, wid = tid >> 6;
    int base = blockIdx.x * BATCH;
    int n = E - base;
    if (n > BATCH) n = BATCH;

    hist[tid] = 0;
    __syncthreads();

    int se[8], de[8];
#pragma unroll
    for (int j = 0; j < 8; ++j) {
        int i = base + j * 512 + tid;
        se[j] = -1;
        de[j] = 0;
        if (i < E) {
            se[j] = src[i];
            de[j] = dst[i];
            atomicAdd(&hist[se[j] >> NB_SHIFT], 1);
        }
    }
    __syncthreads();
    int v = hist[tid];
    int x = v;
#pragma unroll
    for (int off = 1; off < 64; off <<= 1) {
        int y = __shfl_up(x, off, 64);
        if (lane >= off) x += y;
    }
    if (lane == 63) wsum[wid] = x;
    __syncthreads();
    int add = 0;
    for (int w = 0; w < 8; ++w)
        if (w < wid) add += wsum[w];
    int ex = add + x - v;
    excl[tid] = ex;
    cur[tid] = ex;
    __syncthreads();
#pragma unroll
    for (int j = 0; j < 8; ++j) {
        if (se[j] >= 0) {
            int b = se[j] >> NB_SHIFT;
            int pos = atomicAdd(&cur[b], 1);
            staged[pos] = make_int2(se[j], de[j]);
        }
    }
    if (v > 0)
        gbase[tid] = atomicAdd(&bucketCursor[tid], v);
    __syncthreads();
    for (int i = tid; i < n; i += 512) {
        int2 p = staged[i];
        int b = p.x >> NB_SHIFT;
        bucketData[gbase[b] + (i - excl[b])] =
            ((unsigned)(p.x & 255) << 24) | (unsigned)p.y;
    }
}

// ---------------- Kernel 5: bucket-local CSR build (LDS atomics only) -------
__global__ __launch_bounds__(256) void gat_bucket(
    const int* __restrict__ bucketBase, const unsigned* __restrict__ bucketData,
    int* __restrict__ rowptr, int* __restrict__ sortedDst, int N) {
    __shared__ int cnt[256], cur[256];
    __shared__ int wsum[4];
    int b = blockIdx.x;
    int tid = threadIdx.x, lane = tid & 63, wid = tid >> 6;
    int beg = bucketBase[b];
    int end = bucketBase[b + 1];
    int node0 = b << NB_SHIFT;

    cnt[tid] = 0;
    __syncthreads();
    for (int i = beg + tid; i < end; i += 256)
        atomicAdd(&cnt[bucketData[i] >> 24], 1);
    __syncthreads();
    int v = cnt[tid];
    int x = v;
#pragma unroll
    for (int off = 1; off < 64; off <<= 1) {
        int y = __shfl_up(x, off, 64);
        if (lane >= off) x += y;
    }
    if (lane == 63) wsum[wid] = x;
    __syncthreads();
    int add = 0;
    for (int w = 0; w < 4; ++w)
        if (w < wid) add += wsum[w];
    int excl = add + x - v;
    int node = node0 + tid;
    if (node < N) rowptr[node] = beg + excl;
    cur[tid] = beg + excl;
    __syncthreads();
    for (int i = beg + tid; i < end; i += 256) {
        unsigned w = bucketData[i];
        int pos = atomicAdd(&cur[w >> 24], 1);
        sortedDst[pos] = (int)(w & 0xFFFFFFu);
    }
}

// ---------------- Kernel 6: aggregate, 8 nodes/wave, 8-lane subgroup/node ---
__global__ __launch_bounds__(256) void gat_aggregate(
    const int* __restrict__ rowptr,
    const int* __restrict__ sortedDst,
    const float* __restrict__ s1, const float* __restrict__ s2,
    const unsigned short* __restrict__ hb, float* __restrict__ out, int N) {
    int tid = threadIdx.x;
    int node = blockIdx.x * 32 + (tid >> 3);
    if (node >= N) return;
    const int fo = (tid & 7) * 8;    // feature octet owned by this lane

    int beg = rowptr[node];
    int end = rowptr[node + 1];
    float s1s = s1[node];
    float as = s1s + s2[node];
    as = (as >= 0.f) ? as : SLOPE * as;
    as = expf(as);

    float accA[8], accB[8];
    {
        uint4 hv = *(const uint4*)&hb[(size_t)node * F + fo];
        accA[0] = as * __uint_as_float(hv.x << 16);
        accA[1] = as * __uint_as_float(hv.x & 0xFFFF0000u);
        accA[2] = as * __uint_as_float(hv.y << 16);
        accA[3] = as * __uint_as_float(hv.y & 0xFFFF0000u);
        accA[4] = as * __uint_as_float(hv.z << 16);
        accA[5] = as * __uint_as_float(hv.z & 0xFFFF0000u);
        accA[6] = as * __uint_as_float(hv.w << 16);
        accA[7] = as * __uint_as_float(hv.w & 0xFFFF0000u);
    }
#pragma unroll
    for (int i = 0; i < 8; ++i) accB[i] = 0.f;

    float dsum = as;
    int e = beg;
    for (; e + 2 <= end; e += 2) {
        int d0 = sortedDst[e];
        int d1 = sortedDst[e + 1];
        float t0 = s1s + s2[d0];
        float t1 = s1s + s2[d1];
        t0 = (t0 >= 0.f) ? t0 : SLOPE * t0;
        t1 = (t1 >= 0.f) ? t1 : SLOPE * t1;
        float a0 = expf(t0);
        float a1 = expf(t1);
        dsum += a0 + a1;
        uint4 g0 = *(const uint4*)&hb[(size_t)d0 * F + fo];
        uint4 g1 = *(const uint4*)&hb[(size_t)d1 * F + fo];
        accA[0] = fmaf(a0, __uint_as_float(g0.x << 16), accA[0]);
        accA[1] = fmaf(a0, __uint_as_float(g0.x & 0xFFFF0000u), accA[1]);
        accA[2] = fmaf(a0, __uint_as_float(g0.y << 16), accA[2]);
        accA[3] = fmaf(a0, __uint_as_float(g0.y & 0xFFFF0000u), accA[3]);
        accA[4] = fmaf(a0, __uint_as_float(g0.z << 16), accA[4]);
        accA[5] = fmaf(a0, __uint_as_float(g0.z & 0xFFFF0000u), accA[5]);
        accA[6] = fmaf(a0, __uint_as_float(g0.w << 16), accA[6]);
        accA[7] = fmaf(a0, __uint_as_float(g0.w & 0xFFFF0000u), accA[7]);
        accB[0] = fmaf(a1, __uint_as_float(g1.x << 16), accB[0]);
        accB[1] = fmaf(a1, __uint_as_float(g1.x & 0xFFFF0000u), accB[1]);
        accB[2] = fmaf(a1, __uint_as_float(g1.y << 16), accB[2]);
        accB[3] = fmaf(a1, __uint_as_float(g1.y & 0xFFFF0000u), accB[3]);
        accB[4] = fmaf(a1, __uint_as_float(g1.z << 16), accB[4]);
        accB[5] = fmaf(a1, __uint_as_float(g1.z & 0xFFFF0000u), accB[5]);
        accB[6] = fmaf(a1, __uint_as_float(g1.w << 16), accB[6]);
        accB[7] = fmaf(a1, __uint_as_float(g1.w & 0xFFFF0000u), accB[7]);
    }
    if (e < end) {
        int d0 = sortedDst[e];
        float t0 = s1s + s2[d0];
        t0 = (t0 >= 0.f) ? t0 : SLOPE * t0;
        float a0 = expf(t0);
        dsum += a0;
        uint4 g0 = *(const uint4*)&hb[(size_t)d0 * F + fo];
        accA[0] = fmaf(a0, __uint_as_float(g0.x << 16), accA[0]);
        accA[1] = fmaf(a0, __uint_as_float(g0.x & 0xFFFF0000u), accA[1]);
        accA[2] = fmaf(a0, __uint_as_float(g0.y << 16), accA[2]);
        accA[3] = fmaf(a0, __uint_as_float(g0.y & 0xFFFF0000u), accA[3]);
        accA[4] = fmaf(a0, __uint_as_float(g0.z << 16), accA[4]);
        accA[5] = fmaf(a0, __uint_as_float(g0.z & 0xFFFF0000u), accA[5]);
        accA[6] = fmaf(a0, __uint_as_float(g0.w << 16), accA[6]);
        accA[7] = fmaf(a0, __uint_as_float(g0.w & 0xFFFF0000u), accA[7]);
    }

    float inv = 1.0f / dsum;
    float4 r0, r1;
    r0.x = (accA[0] + accB[0]) * inv;
    r0.y = (accA[1] + accB[1]) * inv;
    r0.z = (accA[2] + accB[2]) * inv;
    r0.w = (accA[3] + accB[3]) * inv;
    r1.x = (accA[4] + accB[4]) * inv;
    r1.y = (accA[5] + accB[5]) * inv;
    r1.z = (accA[6] + accB[6]) * inv;
    r1.w = (accA[7] + accB[7]) * inv;
    *(float4*)&out[(size_t)node * F + fo] = r0;
    *(float4*)&out[(size_t)node * F + fo + 4] = r1;
}

extern "C" void kernel_launch(void* const* d_in, const int* in_sizes, int n_in,
                              void* d_out, int out_size, void* d_ws, size_t ws_size,
                              hipStream_t stream) {
    const float* X = (const float*)d_in[0];
    const int* edge = (const int*)d_in[1];
    const float* W = (const float*)d_in[2];
    const float* a = (const float*)d_in[3];

    int N = in_sizes[0] / F;
    int E = in_sizes[1] / 2;
    int NB = (N + 255) >> NB_SHIFT;   // 256-node buckets (<= 512)

    const int* src = edge;
    const int* dst = edge + E;

    // ws: bucketData[E]u32 | hb[N*64]u16 | s1[N] | s2[N] |
    //     partialHist[128*512] | bucketBase[513] | bucketCursor[512] |
    //     rowptr[N+1] | sortedDst[E]
    unsigned* bucketData = (unsigned*)d_ws;
    unsigned short* hb = (unsigned short*)(bucketData + E);
    float* s1 = (float*)(hb + (size_t)N * F);
    float* s2 = s1 + N;
    int* partialHist = (int*)(s2 + N);
    int* bucketBase = partialHist + HIST_BLOCKS * 512;
    int* bucketCursor = bucketBase + 513;
    int* rowptr = bucketCursor + 512;
    int* sortedDst = rowptr + (N + 1);

    float* out = (float*)d_out;

    int gemmBlocks = (N + 127) / 128;
    gat_gemm<<<gemmBlocks, 256, 0, stream>>>(X, W, a, hb, s1, s2, N);

    gat_histb<<<HIST_BLOCKS, 256, 0, stream>>>(src, partialHist, E);

    gat_scan0<<<1, 512, 0, stream>>>(partialHist, bucketBase, bucketCursor,
                                     rowptr + N, NB);

    int binBlocks = (E + BATCH - 1) / BATCH;
    gat_bin<<<binBlocks, 512, 0, stream>>>(src, dst, bucketCursor, bucketData, E);

    gat_bucket<<<NB, 256, 0, stream>>>(bucketBase, bucketData, rowptr,
                                       sortedDst, N);

    int aggBlocks = (N + 31) / 32;
    gat_aggregate<<<aggBlocks, 256, 0, stream>>>(rowptr, sortedDst,
                                                 s1, s2, hb, out, N);
}

// Round 15
// 105.783 us; speedup vs baseline: 1.1965x; 1.1031x over previous
//
#include <hip/hip_runtime.h>
#include <hip/hip_bf16.h>

#define F 64
#define SLOPE 0.2f
#define NB_SHIFT 8     // 256 nodes per coarse bucket
#define BATCH 4096     // edges per gat_bin block
#define HIST_BLOCKS 128

typedef __attribute__((ext_vector_type(8))) short bf16x8;
typedef __attribute__((ext_vector_type(4))) float f32x4;

__device__ inline unsigned short f2bf(float f) {
    unsigned u = __float_as_uint(f);
    unsigned r = (u + 0x7FFFu + ((u >> 16) & 1u)) >> 16;
    return (unsigned short)r;
}

// ---------------- Kernel 1: bucket histogram + (block 0) W-operand prep -----
// Block 0 additionally packs Wp (bf16 B-fragments for the MFMA gemm) and
// computes w1 = W @ a[:64], w2 = W @ a[64:] in fp32 (exact s1/s2 path).
__global__ __launch_bounds__(256) void gat_histb(
    const int* __restrict__ src, int* __restrict__ partialHist, int E,
    const float* __restrict__ W, const float* __restrict__ a,
    unsigned short* __restrict__ Wp, float* __restrict__ w1,
    float* __restrict__ w2) {
    __shared__ int lh[512];
    int tid = threadIdx.x;
    for (int i = tid; i < 512; i += 256) lh[i] = 0;
    __syncthreads();
    for (int i = blockIdx.x * 256 + tid; i < E; i += HIST_BLOCKS * 256)
        atomicAdd(&lh[src[i] >> NB_SHIFT], 1);
    __syncthreads();
    for (int i = tid; i < 512; i += 256)
        partialHist[blockIdx.x * 512 + i] = lh[i];

    if (blockIdx.x == 0) {
        if (tid < 64) {
            // B fragment packing: frag f = cg*2 + kc; lane tid:
            // col = cg*16 + (tid&15), k = kc*32 + (tid>>4)*8 + j, j = 0..7
#pragma unroll
            for (int f = 0; f < 8; ++f) {
                int cg = f >> 1, kc = f & 1;
                int col = cg * 16 + (tid & 15);
                unsigned short us[8];
#pragma unroll
                for (int j = 0; j < 8; ++j) {
                    int k = kc * 32 + (tid >> 4) * 8 + j;
                    us[j] = f2bf(W[k * F + col]);
                }
                uint4 pk;
                pk.x = us[0] | ((unsigned)us[1] << 16);
                pk.y = us[2] | ((unsigned)us[3] << 16);
                pk.z = us[4] | ((unsigned)us[5] << 16);
                pk.w = us[6] | ((unsigned)us[7] << 16);
                *(uint4*)&Wp[(f * 64 + tid) * 8] = pk;
            }
        } else if (tid < 128) {
            int k = tid - 64;
            float acc1 = 0.f, acc2 = 0.f;
#pragma unroll
            for (int n = 0; n < F; ++n) {
                float wv = W[k * F + n];
                acc1 = fmaf(wv, a[n], acc1);
                acc2 = fmaf(wv, a[F + n], acc2);
            }
            w1[k] = acc1;
            w2[k] = acc2;
        }
    }
}

// ---------------- Kernel 2: MFMA gemm: h(bf16) = X @ W, exact s1/s2 ---------
// One wave per 16-row tile, 4 waves/block, no LDS, no barriers.
// A frag: row = l&15, k = (l>>4)*8+j (+32 for kc=1). B frags preloaded from Wp.
// C/D: col = lane&15, row = (lane>>4)*4 + reg.
__global__ __launch_bounds__(256) void gat_gemm_mfma(
    const float* __restrict__ X, const unsigned short* __restrict__ Wp,
    const float* __restrict__ w1, const float* __restrict__ w2,
    unsigned short* __restrict__ hb, float* __restrict__ s1,
    float* __restrict__ s2, int N) {
    int tid = threadIdx.x;
    int lane = tid & 63;
    int wv = tid >> 6;
    int rowBase = blockIdx.x * 64 + wv * 16;
    if (rowBase >= N) return;
    int lrow = lane & 15;
    int kg = lane >> 4;          // 0..3
    int row = rowBase + lrow;
    int rclamp = (row < N) ? row : (N - 1);

    // Load this lane's X values (fp32): xr[0..7] = kc0, xr[8..15] = kc1
    const float* xp = &X[(size_t)rclamp * F + kg * 8];
    float4 u0 = *(const float4*)(xp + 0);
    float4 u1 = *(const float4*)(xp + 4);
    float4 u2 = *(const float4*)(xp + 32);
    float4 u3 = *(const float4*)(xp + 36);
    float xr[16] = {u0.x, u0.y, u0.z, u0.w, u1.x, u1.y, u1.z, u1.w,
                    u2.x, u2.y, u2.z, u2.w, u3.x, u3.y, u3.z, u3.w};

    // Convert A fragments to bf16
    bf16x8 a0, a1;
#pragma unroll
    for (int j = 0; j < 8; ++j) {
        a0[j] = (short)f2bf(xr[j]);
        a1[j] = (short)f2bf(xr[8 + j]);
    }

    // Load 8 packed B fragments
    bf16x8 bf0 = *(const bf16x8*)&Wp[(0 * 64 + lane) * 8];
    bf16x8 bf1 = *(const bf16x8*)&Wp[(1 * 64 + lane) * 8];
    bf16x8 bf2 = *(const bf16x8*)&Wp[(2 * 64 + lane) * 8];
    bf16x8 bf3 = *(const bf16x8*)&Wp[(3 * 64 + lane) * 8];
    bf16x8 bf4 = *(const bf16x8*)&Wp[(4 * 64 + lane) * 8];
    bf16x8 bf5 = *(const bf16x8*)&Wp[(5 * 64 + lane) * 8];
    bf16x8 bf6 = *(const bf16x8*)&Wp[(6 * 64 + lane) * 8];
    bf16x8 bf7 = *(const bf16x8*)&Wp[(7 * 64 + lane) * 8];

    f32x4 acc0 = {0.f, 0.f, 0.f, 0.f};
    f32x4 acc1v = {0.f, 0.f, 0.f, 0.f};
    f32x4 acc2v = {0.f, 0.f, 0.f, 0.f};
    f32x4 acc3 = {0.f, 0.f, 0.f, 0.f};
    acc0 = __builtin_amdgcn_mfma_f32_16x16x32_bf16(a0, bf0, acc0, 0, 0, 0);
    acc0 = __builtin_amdgcn_mfma_f32_16x16x32_bf16(a1, bf1, acc0, 0, 0, 0);
    acc1v = __builtin_amdgcn_mfma_f32_16x16x32_bf16(a0, bf2, acc1v, 0, 0, 0);
    acc1v = __builtin_amdgcn_mfma_f32_16x16x32_bf16(a1, bf3, acc1v, 0, 0, 0);
    acc2v = __builtin_amdgcn_mfma_f32_16x16x32_bf16(a0, bf4, acc2v, 0, 0, 0);
    acc2v = __builtin_amdgcn_mfma_f32_16x16x32_bf16(a1, bf5, acc2v, 0, 0, 0);
    acc3 = __builtin_amdgcn_mfma_f32_16x16x32_bf16(a0, bf6, acc3, 0, 0, 0);
    acc3 = __builtin_amdgcn_mfma_f32_16x16x32_bf16(a1, bf7, acc3, 0, 0, 0);

    // C store: row = rowBase + kg*4 + r, col = cg*16 + lrow
#pragma unroll
    for (int r = 0; r < 4; ++r) {
        int ro = rowBase + kg * 4 + r;
        if (ro < N) {
            size_t rb = (size_t)ro * F + lrow;
            hb[rb + 0] = f2bf(acc0[r]);
            hb[rb + 16] = f2bf(acc1v[r]);
            hb[rb + 32] = f2bf(acc2v[r]);
            hb[rb + 48] = f2bf(acc3[r]);
        }
    }

    // Exact s1/s2 from fp32 X: s1[row] = X[row,:] . w1
    float4 wa0 = *(const float4*)&w1[kg * 8];
    float4 wa1 = *(const float4*)&w1[kg * 8 + 4];
    float4 wa2 = *(const float4*)&w1[32 + kg * 8];
    float4 wa3 = *(const float4*)&w1[32 + kg * 8 + 4];
    float4 wb0 = *(const float4*)&w2[kg * 8];
    float4 wb1 = *(const float4*)&w2[kg * 8 + 4];
    float4 wb2 = *(const float4*)&w2[32 + kg * 8];
    float4 wb3 = *(const float4*)&w2[32 + kg * 8 + 4];
    float wv1[16] = {wa0.x, wa0.y, wa0.z, wa0.w, wa1.x, wa1.y, wa1.z, wa1.w,
                     wa2.x, wa2.y, wa2.z, wa2.w, wa3.x, wa3.y, wa3.z, wa3.w};
    float wv2[16] = {wb0.x, wb0.y, wb0.z, wb0.w, wb1.x, wb1.y, wb1.z, wb1.w,
                     wb2.x, wb2.y, wb2.z, wb2.w, wb3.x, wb3.y, wb3.z, wb3.w};
    float p = 0.f, q = 0.f;
#pragma unroll
    for (int j = 0; j < 16; ++j) {
        p = fmaf(xr[j], wv1[j], p);
        q = fmaf(xr[j], wv2[j], q);
    }
    p += __shfl_xor(p, 16, 64);
    p += __shfl_xor(p, 32, 64);
    q += __shfl_xor(q, 16, 64);
    q += __shfl_xor(q, 32, 64);
    if (lane < 16 && row < N) {
        s1[row] = p;
        s2[row] = q;
    }
}

// ---------------- Kernel 3: sum partials + scan -> bucketBase/Cursor --------
__global__ __launch_bounds__(512) void gat_scan0(
    const int* __restrict__ partialHist, int* __restrict__ bucketBase,
    int* __restrict__ bucketCursor, int* __restrict__ rowptrN, int NB) {
    __shared__ int wsum[8];
    int tid = threadIdx.x, lane = tid & 63, wid = tid >> 6;
    int v = 0;
    for (int p = 0; p < HIST_BLOCKS; ++p)
        v += partialHist[p * 512 + tid];
    int x = v;
#pragma unroll
    for (int off = 1; off < 64; off <<= 1) {
        int y = __shfl_up(x, off, 64);
        if (lane >= off) x += y;
    }
    if (lane == 63) wsum[wid] = x;
    __syncthreads();
    int add = 0;
    for (int w = 0; w < 8; ++w)
        if (w < wid) add += wsum[w];
    int excl = add + x - v;
    if (tid < NB) {
        bucketBase[tid] = excl;
        bucketCursor[tid] = excl;
    }
    if (tid == NB - 1) {
        bucketBase[NB] = excl + v;   // == E
        rowptrN[0] = excl + v;       // rowptr[N] = E
    }
}

// ---------------- Kernel 4: coarse radix partition by src>>8, packed out ----
// bucketData element: (src & 255) << 24 | dst   (dst < 2^24)
__global__ __launch_bounds__(512) void gat_bin(
    const int* __restrict__ src, const int* __restrict__ dst,
    int* __restrict__ bucketCursor, unsigned* __restrict__ bucketData, int E) {
    __shared__ int hist[512], excl[512], gbase[512], cur[512];
    __shared__ int wsum[8];
    __shared__ int2 staged[BATCH];
    int tid = threadIdx.x, lane = tid & 63, wid = tid >> 6;
    int base = blockIdx.x * BATCH;
    int n = E - base;
    if (n > BATCH) n = BATCH;

    hist[tid] = 0;
    __syncthreads();

    int se[8], de[8];
#pragma unroll
    for (int j = 0; j < 8; ++j) {
        int i = base + j * 512 + tid;
        se[j] = -1;
        de[j] = 0;
        if (i < E) {
            se[j] = src[i];
            de[j] = dst[i];
            atomicAdd(&hist[se[j] >> NB_SHIFT], 1);
        }
    }
    __syncthreads();
    int v = hist[tid];
    int x = v;
#pragma unroll
    for (int off = 1; off < 64; off <<= 1) {
        int y = __shfl_up(x, off, 64);
        if (lane >= off) x += y;
    }
    if (lane == 63) wsum[wid] = x;
    __syncthreads();
    int add = 0;
    for (int w = 0; w < 8; ++w)
        if (w < wid) add += wsum[w];
    int ex = add + x - v;
    excl[tid] = ex;
    cur[tid] = ex;
    __syncthreads();
#pragma unroll
    for (int j = 0; j < 8; ++j) {
        if (se[j] >= 0) {
            int b = se[j] >> NB_SHIFT;
            int pos = atomicAdd(&cur[b], 1);
            staged[pos] = make_int2(se[j], de[j]);
        }
    }
    if (v > 0)
        gbase[tid] = atomicAdd(&bucketCursor[tid], v);
    __syncthreads();
    for (int i = tid; i < n; i += 512) {
        int2 p = staged[i];
        int b = p.x >> NB_SHIFT;
        bucketData[gbase[b] + (i - excl[b])] =
            ((unsigned)(p.x & 255) << 24) | (unsigned)p.y;
    }
}

// ---------------- Kernel 5: bucket-local CSR build (LDS atomics only) -------
__global__ __launch_bounds__(256) void gat_bucket(
    const int* __restrict__ bucketBase, const unsigned* __restrict__ bucketData,
    int* __restrict__ rowptr, int* __restrict__ sortedDst, int N) {
    __shared__ int cnt[256], cur[256];
    __shared__ int wsum[4];
    int b = blockIdx.x;
    int tid = threadIdx.x, lane = tid & 63, wid = tid >> 6;
    int beg = bucketBase[b];
    int end = bucketBase[b + 1];
    int node0 = b << NB_SHIFT;

    cnt[tid] = 0;
    __syncthreads();
    for (int i = beg + tid; i < end; i += 256)
        atomicAdd(&cnt[bucketData[i] >> 24], 1);
    __syncthreads();
    int v = cnt[tid];
    int x = v;
#pragma unroll
    for (int off = 1; off < 64; off <<= 1) {
        int y = __shfl_up(x, off, 64);
        if (lane >= off) x += y;
    }
    if (lane == 63) wsum[wid] = x;
    __syncthreads();
    int add = 0;
    for (int w = 0; w < 4; ++w)
        if (w < wid) add += wsum[w];
    int excl = add + x - v;
    int node = node0 + tid;
    if (node < N) rowptr[node] = beg + excl;
    cur[tid] = beg + excl;
    __syncthreads();
    for (int i = beg + tid; i < end; i += 256) {
        unsigned w = bucketData[i];
        int pos = atomicAdd(&cur[w >> 24], 1);
        sortedDst[pos] = (int)(w & 0xFFFFFFu);
    }
}

// ---------------- Kernel 6: aggregate, 8 nodes/wave, 8-lane subgroup/node ---
__global__ __launch_bounds__(256) void gat_aggregate(
    const int* __restrict__ rowptr,
    const int* __restrict__ sortedDst,
    const float* __restrict__ s1, const float* __restrict__ s2,
    const unsigned short* __restrict__ hb, float* __restrict__ out, int N) {
    int tid = threadIdx.x;
    int node = blockIdx.x * 32 + (tid >> 3);
    if (node >= N) return;
    const int fo = (tid & 7) * 8;    // feature octet owned by this lane

    int beg = rowptr[node];
    int end = rowptr[node + 1];
    float s1s = s1[node];
    float as = s1s + s2[node];
    as = (as >= 0.f) ? as : SLOPE * as;
    as = expf(as);

    float accA[8], accB[8];
    {
        uint4 hv = *(const uint4*)&hb[(size_t)node * F + fo];
        accA[0] = as * __uint_as_float(hv.x << 16);
        accA[1] = as * __uint_as_float(hv.x & 0xFFFF0000u);
        accA[2] = as * __uint_as_float(hv.y << 16);
        accA[3] = as * __uint_as_float(hv.y & 0xFFFF0000u);
        accA[4] = as * __uint_as_float(hv.z << 16);
        accA[5] = as * __uint_as_float(hv.z & 0xFFFF0000u);
        accA[6] = as * __uint_as_float(hv.w << 16);
        accA[7] = as * __uint_as_float(hv.w & 0xFFFF0000u);
    }
#pragma unroll
    for (int i = 0; i < 8; ++i) accB[i] = 0.f;

    float dsum = as;
    int e = beg;
    for (; e + 2 <= end; e += 2) {
        int d0 = sortedDst[e];
        int d1 = sortedDst[e + 1];
        float t0 = s1s + s2[d0];
        float t1 = s1s + s2[d1];
        t0 = (t0 >= 0.f) ? t0 : SLOPE * t0;
        t1 = (t1 >= 0.f) ? t1 : SLOPE * t1;
        float a0 = expf(t0);
        float a1 = expf(t1);
        dsum += a0 + a1;
        uint4 g0 = *(const uint4*)&hb[(size_t)d0 * F + fo];
        uint4 g1 = *(const uint4*)&hb[(size_t)d1 * F + fo];
        accA[0] = fmaf(a0, __uint_as_float(g0.x << 16), accA[0]);
        accA[1] = fmaf(a0, __uint_as_float(g0.x & 0xFFFF0000u), accA[1]);
        accA[2] = fmaf(a0, __uint_as_float(g0.y << 16), accA[2]);
        accA[3] = fmaf(a0, __uint_as_float(g0.y & 0xFFFF0000u), accA[3]);
        accA[4] = fmaf(a0, __uint_as_float(g0.z << 16), accA[4]);
        accA[5] = fmaf(a0, __uint_as_float(g0.z & 0xFFFF0000u), accA[5]);
        accA[6] = fmaf(a0, __uint_as_float(g0.w << 16), accA[6]);
        accA[7] = fmaf(a0, __uint_as_float(g0.w & 0xFFFF0000u), accA[7]);
        accB[0] = fmaf(a1, __uint_as_float(g1.x << 16), accB[0]);
        accB[1] = fmaf(a1, __uint_as_float(g1.x & 0xFFFF0000u), accB[1]);
        accB[2] = fmaf(a1, __uint_as_float(g1.y << 16), accB[2]);
        accB[3] = fmaf(a1, __uint_as_float(g1.y & 0xFFFF0000u), accB[3]);
        accB[4] = fmaf(a1, __uint_as_float(g1.z << 16), accB[4]);
        accB[5] = fmaf(a1, __uint_as_float(g1.z & 0xFFFF0000u), accB[5]);
        accB[6] = fmaf(a1, __uint_as_float(g1.w << 16), accB[6]);
        accB[7] = fmaf(a1, __uint_as_float(g1.w & 0xFFFF0000u), accB[7]);
    }
    if (e < end) {
        int d0 = sortedDst[e];
        float t0 = s1s + s2[d0];
        t0 = (t0 >= 0.f) ? t0 : SLOPE * t0;
        float a0 = expf(t0);
        dsum += a0;
        uint4 g0 = *(const uint4*)&hb[(size_t)d0 * F + fo];
        accA[0] = fmaf(a0, __uint_as_float(g0.x << 16), accA[0]);
        accA[1] = fmaf(a0, __uint_as_float(g0.x & 0xFFFF0000u), accA[1]);
        accA[2] = fmaf(a0, __uint_as_float(g0.y << 16), accA[2]);
        accA[3] = fmaf(a0, __uint_as_float(g0.y & 0xFFFF0000u), accA[3]);
        accA[4] = fmaf(a0, __uint_as_float(g0.z << 16), accA[4]);
        accA[5] = fmaf(a0, __uint_as_float(g0.z & 0xFFFF0000u), accA[5]);
        accA[6] = fmaf(a0, __uint_as_float(g0.w << 16), accA[6]);
        accA[7] = fmaf(a0, __uint_as_float(g0.w & 0xFFFF0000u), accA[7]);
    }

    float inv = 1.0f / dsum;
    float4 r0, r1;
    r0.x = (accA[0] + accB[0]) * inv;
    r0.y = (accA[1] + accB[1]) * inv;
    r0.z = (accA[2] + accB[2]) * inv;
    r0.w = (accA[3] + accB[3]) * inv;
    r1.x = (accA[4] + accB[4]) * inv;
    r1.y = (accA[5] + accB[5]) * inv;
    r1.z = (accA[6] + accB[6]) * inv;
    r1.w = (accA[7] + accB[7]) * inv;
    *(float4*)&out[(size_t)node * F + fo] = r0;
    *(float4*)&out[(size_t)node * F + fo + 4] = r1;
}

extern "C" void kernel_launch(void* const* d_in, const int* in_sizes, int n_in,
                              void* d_out, int out_size, void* d_ws, size_t ws_size,
                              hipStream_t stream) {
    const float* X = (const float*)d_in[0];
    const int* edge = (const int*)d_in[1];
    const float* W = (const float*)d_in[2];
    const float* a = (const float*)d_in[3];

    int N = in_sizes[0] / F;
    int E = in_sizes[1] / 2;
    int NB = (N + 255) >> NB_SHIFT;   // 256-node buckets (<= 512)

    const int* src = edge;
    const int* dst = edge + E;

    // ws: bucketData[E]u32 | hb[N*64]u16 | s1[N] | s2[N] |
    //     partialHist[128*512] | bucketBase[513] | bucketCursor[512] |
    //     rowptr[N+1] | sortedDst[E] | Wp[4096]u16 | w1[64] | w2[64]
    unsigned* bucketData = (unsigned*)d_ws;
    unsigned short* hb = (unsigned short*)(bucketData + E);
    float* s1 = (float*)(hb + (size_t)N * F);
    float* s2 = s1 + N;
    int* partialHist = (int*)(s2 + N);
    int* bucketBase = partialHist + HIST_BLOCKS * 512;
    int* bucketCursor = bucketBase + 513;
    int* rowptr = bucketCursor + 512;
    int* sortedDst = rowptr + (N + 1);
    unsigned short* Wp = (unsigned short*)(sortedDst + E);
    float* w1 = (float*)(Wp + 4096);
    float* w2 = w1 + 64;

    float* out = (float*)d_out;

    // histb first: also preps Wp/w1/w2 for the MFMA gemm
    gat_histb<<<HIST_BLOCKS, 256, 0, stream>>>(src, partialHist, E, W, a,
                                               Wp, w1, w2);

    int gemmBlocks = (N + 63) / 64;
    gat_gemm_mfma<<<gemmBlocks, 256, 0, stream>>>(X, Wp, w1, w2, hb, s1, s2, N);

    gat_scan0<<<1, 512, 0, stream>>>(partialHist, bucketBase, bucketCursor,
                                     rowptr + N, NB);

    int binBlocks = (E + BATCH - 1) / BATCH;
    gat_bin<<<binBlocks, 512, 0, stream>>>(src, dst, bucketCursor, bucketData, E);

    gat_bucket<<<NB, 256, 0, stream>>>(bucketBase, bucketData, rowptr,
                                       sortedDst, N);

    int aggBlocks = (N + 31) / 32;
    gat_aggregate<<<aggBlocks, 256, 0, stream>>>(rowptr, sortedDst,
                                                 s1, s2, hb, out, N);
}

// Round 16
// 104.954 us; speedup vs baseline: 1.2059x; 1.0079x over previous
//
#include <hip/hip_runtime.h>
#include <hip/hip_bf16.h>

#define F 64
#define SLOPE 0.2f
#define NB_SHIFT 8     // 256 nodes per coarse bucket
#define BATCH 4096     // edges per gat_bin block
#define HIST_BLOCKS 128

typedef __attribute__((ext_vector_type(8))) short bf16x8;
typedef __attribute__((ext_vector_type(4))) float f32x4;

__device__ inline unsigned short f2bf(float f) {
    unsigned u = __float_as_uint(f);
    unsigned r = (u + 0x7FFFu + ((u >> 16) & 1u)) >> 16;
    return (unsigned short)r;
}

// ---------------- Kernel 0: prep Wp (bf16 B-frags), w1/w2 (1 block) ---------
__global__ __launch_bounds__(256) void gat_prep(
    const float* __restrict__ W, const float* __restrict__ a,
    unsigned short* __restrict__ Wp, float* __restrict__ w1,
    float* __restrict__ w2) {
    int tid = threadIdx.x;
    if (tid < 64) {
        // B fragment f = cg*2 + kc; lane tid: col = cg*16 + (tid&15),
        // k = kc*32 + (tid>>4)*8 + j
#pragma unroll
        for (int f = 0; f < 8; ++f) {
            int cg = f >> 1, kc = f & 1;
            int col = cg * 16 + (tid & 15);
            unsigned short us[8];
#pragma unroll
            for (int j = 0; j < 8; ++j) {
                int k = kc * 32 + (tid >> 4) * 8 + j;
                us[j] = f2bf(W[k * F + col]);
            }
            uint4 pk;
            pk.x = us[0] | ((unsigned)us[1] << 16);
            pk.y = us[2] | ((unsigned)us[3] << 16);
            pk.z = us[4] | ((unsigned)us[5] << 16);
            pk.w = us[6] | ((unsigned)us[7] << 16);
            *(uint4*)&Wp[(f * 64 + tid) * 8] = pk;
        }
    } else if (tid < 128) {
        int k = tid - 64;
        float acc1 = 0.f, acc2 = 0.f;
#pragma unroll
        for (int n = 0; n < F; ++n) {
            float wv = W[k * F + n];
            acc1 = fmaf(wv, a[n], acc1);
            acc2 = fmaf(wv, a[F + n], acc2);
        }
        w1[k] = acc1;
        w2[k] = acc2;
    }
}

// ---------------- Kernel 1: fused [MFMA gemm] ∥ [bucket histogram] ----------
// Blocks [0, gemmBlocks): gemm (no LDS use). Blocks [gemmBlocks, +128): hist
// partials (2 KB LDS). Tiny static LDS so occupancy of both parts is intact.
__global__ __launch_bounds__(256) void gat_gemm_hist(
    const float* __restrict__ X, const unsigned short* __restrict__ Wp,
    const float* __restrict__ w1, const float* __restrict__ w2,
    unsigned short* __restrict__ hb, float* __restrict__ s1,
    float* __restrict__ s2, int N,
    const int* __restrict__ src, int* __restrict__ partialHist, int E,
    int gemmBlocks) {
    __shared__ int lh[512];
    int tid = threadIdx.x;

    if ((int)blockIdx.x >= gemmBlocks) {
        // ---- histogram part ----
        int hbid = blockIdx.x - gemmBlocks;
        for (int i = tid; i < 512; i += 256) lh[i] = 0;
        __syncthreads();
        for (int i = hbid * 256 + tid; i < E; i += HIST_BLOCKS * 256)
            atomicAdd(&lh[src[i] >> NB_SHIFT], 1);
        __syncthreads();
        for (int i = tid; i < 512; i += 256)
            partialHist[hbid * 512 + i] = lh[i];
        return;
    }

    // ---- MFMA gemm part (one wave per 16-row tile, no LDS, no barriers) ----
    int lane = tid & 63;
    int wv = tid >> 6;
    int rowBase = blockIdx.x * 64 + wv * 16;
    if (rowBase >= N) return;
    int lrow = lane & 15;
    int kg = lane >> 4;          // 0..3
    int row = rowBase + lrow;
    int rclamp = (row < N) ? row : (N - 1);

    const float* xp = &X[(size_t)rclamp * F + kg * 8];
    float4 u0 = *(const float4*)(xp + 0);
    float4 u1 = *(const float4*)(xp + 4);
    float4 u2 = *(const float4*)(xp + 32);
    float4 u3 = *(const float4*)(xp + 36);
    float xr[16] = {u0.x, u0.y, u0.z, u0.w, u1.x, u1.y, u1.z, u1.w,
                    u2.x, u2.y, u2.z, u2.w, u3.x, u3.y, u3.z, u3.w};

    bf16x8 a0, a1;
#pragma unroll
    for (int j = 0; j < 8; ++j) {
        a0[j] = (short)f2bf(xr[j]);
        a1[j] = (short)f2bf(xr[8 + j]);
    }

    bf16x8 bf0 = *(const bf16x8*)&Wp[(0 * 64 + lane) * 8];
    bf16x8 bf1 = *(const bf16x8*)&Wp[(1 * 64 + lane) * 8];
    bf16x8 bf2 = *(const bf16x8*)&Wp[(2 * 64 + lane) * 8];
    bf16x8 bf3 = *(const bf16x8*)&Wp[(3 * 64 + lane) * 8];
    bf16x8 bf4 = *(const bf16x8*)&Wp[(4 * 64 + lane) * 8];
    bf16x8 bf5 = *(const bf16x8*)&Wp[(5 * 64 + lane) * 8];
    bf16x8 bf6 = *(const bf16x8*)&Wp[(6 * 64 + lane) * 8];
    bf16x8 bf7 = *(const bf16x8*)&Wp[(7 * 64 + lane) * 8];

    f32x4 acc0 = {0.f, 0.f, 0.f, 0.f};
    f32x4 acc1v = {0.f, 0.f, 0.f, 0.f};
    f32x4 acc2v = {0.f, 0.f, 0.f, 0.f};
    f32x4 acc3 = {0.f, 0.f, 0.f, 0.f};
    acc0 = __builtin_amdgcn_mfma_f32_16x16x32_bf16(a0, bf0, acc0, 0, 0, 0);
    acc0 = __builtin_amdgcn_mfma_f32_16x16x32_bf16(a1, bf1, acc0, 0, 0, 0);
    acc1v = __builtin_amdgcn_mfma_f32_16x16x32_bf16(a0, bf2, acc1v, 0, 0, 0);
    acc1v = __builtin_amdgcn_mfma_f32_16x16x32_bf16(a1, bf3, acc1v, 0, 0, 0);
    acc2v = __builtin_amdgcn_mfma_f32_16x16x32_bf16(a0, bf4, acc2v, 0, 0, 0);
    acc2v = __builtin_amdgcn_mfma_f32_16x16x32_bf16(a1, bf5, acc2v, 0, 0, 0);
    acc3 = __builtin_amdgcn_mfma_f32_16x16x32_bf16(a0, bf6, acc3, 0, 0, 0);
    acc3 = __builtin_amdgcn_mfma_f32_16x16x32_bf16(a1, bf7, acc3, 0, 0, 0);

#pragma unroll
    for (int r = 0; r < 4; ++r) {
        int ro = rowBase + kg * 4 + r;
        if (ro < N) {
            size_t rb = (size_t)ro * F + lrow;
            hb[rb + 0] = f2bf(acc0[r]);
            hb[rb + 16] = f2bf(acc1v[r]);
            hb[rb + 32] = f2bf(acc2v[r]);
            hb[rb + 48] = f2bf(acc3[r]);
        }
    }

    // Exact s1/s2 from fp32 X
    float4 wa0 = *(const float4*)&w1[kg * 8];
    float4 wa1 = *(const float4*)&w1[kg * 8 + 4];
    float4 wa2 = *(const float4*)&w1[32 + kg * 8];
    float4 wa3 = *(const float4*)&w1[32 + kg * 8 + 4];
    float4 wb0 = *(const float4*)&w2[kg * 8];
    float4 wb1 = *(const float4*)&w2[kg * 8 + 4];
    float4 wb2 = *(const float4*)&w2[32 + kg * 8];
    float4 wb3 = *(const float4*)&w2[32 + kg * 8 + 4];
    float wv1[16] = {wa0.x, wa0.y, wa0.z, wa0.w, wa1.x, wa1.y, wa1.z, wa1.w,
                     wa2.x, wa2.y, wa2.z, wa2.w, wa3.x, wa3.y, wa3.z, wa3.w};
    float wv2[16] = {wb0.x, wb0.y, wb0.z, wb0.w, wb1.x, wb1.y, wb1.z, wb1.w,
                     wb2.x, wb2.y, wb2.z, wb2.w, wb3.x, wb3.y, wb3.z, wb3.w};
    float p = 0.f, q = 0.f;
#pragma unroll
    for (int j = 0; j < 16; ++j) {
        p = fmaf(xr[j], wv1[j], p);
        q = fmaf(xr[j], wv2[j], q);
    }
    p += __shfl_xor(p, 16, 64);
    p += __shfl_xor(p, 32, 64);
    q += __shfl_xor(q, 16, 64);
    q += __shfl_xor(q, 32, 64);
    if (lane < 16 && row < N) {
        s1[row] = p;
        s2[row] = q;
    }
}

// ---------------- Kernel 2: sum partials + scan -> bucketBase/Cursor --------
__global__ __launch_bounds__(512) void gat_scan0(
    const int* __restrict__ partialHist, int* __restrict__ bucketBase,
    int* __restrict__ bucketCursor, int* __restrict__ rowptrN, int NB) {
    __shared__ int wsum[8];
    int tid = threadIdx.x, lane = tid & 63, wid = tid >> 6;
    int v = 0;
    for (int p = 0; p < HIST_BLOCKS; ++p)
        v += partialHist[p * 512 + tid];
    int x = v;
#pragma unroll
    for (int off = 1; off < 64; off <<= 1) {
        int y = __shfl_up(x, off, 64);
        if (lane >= off) x += y;
    }
    if (lane == 63) wsum[wid] = x;
    __syncthreads();
    int add = 0;
    for (int w = 0; w < 8; ++w)
        if (w < wid) add += wsum[w];
    int excl = add + x - v;
    if (tid < NB) {
        bucketBase[tid] = excl;
        bucketCursor[tid] = excl;
    }
    if (tid == NB - 1) {
        bucketBase[NB] = excl + v;   // == E
        rowptrN[0] = excl + v;       // rowptr[N] = E
    }
}

// ---------------- Kernel 3: coarse radix partition by src>>8, packed out ----
// bucketData element: (src & 255) << 24 | dst   (dst < 2^24)
__global__ __launch_bounds__(512) void gat_bin(
    const int* __restrict__ src, const int* __restrict__ dst,
    int* __restrict__ bucketCursor, unsigned* __restrict__ bucketData, int E) {
    __shared__ int hist[512], excl[512], gbase[512], cur[512];
    __shared__ int wsum[8];
    __shared__ int2 staged[BATCH];
    int tid = threadIdx.x, lane = tid & 63, wid = tid >> 6;
    int base = blockIdx.x * BATCH;
    int n = E - base;
    if (n > BATCH) n = BATCH;

    hist[tid] = 0;
    __syncthreads();

    int se[8], de[8];
#pragma unroll
    for (int j = 0; j < 8; ++j) {
        int i = base + j * 512 + tid;
        se[j] = -1;
        de[j] = 0;
        if (i < E) {
            se[j] = src[i];
            de[j] = dst[i];
            atomicAdd(&hist[se[j] >> NB_SHIFT], 1);
        }
    }
    __syncthreads();
    int v = hist[tid];
    int x = v;
#pragma unroll
    for (int off = 1; off < 64; off <<= 1) {
        int y = __shfl_up(x, off, 64);
        if (lane >= off) x += y;
    }
    if (lane == 63) wsum[wid] = x;
    __syncthreads();
    int add = 0;
    for (int w = 0; w < 8; ++w)
        if (w < wid) add += wsum[w];
    int ex = add + x - v;
    excl[tid] = ex;
    cur[tid] = ex;
    __syncthreads();
#pragma unroll
    for (int j = 0; j < 8; ++j) {
        if (se[j] >= 0) {
            int b = se[j] >> NB_SHIFT;
            int pos = atomicAdd(&cur[b], 1);
            staged[pos] = make_int2(se[j], de[j]);
        }
    }
    if (v > 0)
        gbase[tid] = atomicAdd(&bucketCursor[tid], v);
    __syncthreads();
    for (int i = tid; i < n; i += 512) {
        int2 p = staged[i];
        int b = p.x >> NB_SHIFT;
        bucketData[gbase[b] + (i - excl[b])] =
            ((unsigned)(p.x & 255) << 24) | (unsigned)p.y;
    }
}

// ---------------- Kernel 4: bucket-local CSR build (LDS atomics only) -------
__global__ __launch_bounds__(256) void gat_bucket(
    const int* __restrict__ bucketBase, const unsigned* __restrict__ bucketData,
    int* __restrict__ rowptr, int* __restrict__ sortedDst, int N) {
    __shared__ int cnt[256], cur[256];
    __shared__ int wsum[4];
    int b = blockIdx.x;
    int tid = threadIdx.x, lane = tid & 63, wid = tid >> 6;
    int beg = bucketBase[b];
    int end = bucketBase[b + 1];
    int node0 = b << NB_SHIFT;

    cnt[tid] = 0;
    __syncthreads();
    for (int i = beg + tid; i < end; i += 256)
        atomicAdd(&cnt[bucketData[i] >> 24], 1);
    __syncthreads();
    int v = cnt[tid];
    int x = v;
#pragma unroll
    for (int off = 1; off < 64; off <<= 1) {
        int y = __shfl_up(x, off, 64);
        if (lane >= off) x += y;
    }
    if (lane == 63) wsum[wid] = x;
    __syncthreads();
    int add = 0;
    for (int w = 0; w < 4; ++w)
        if (w < wid) add += wsum[w];
    int excl = add + x - v;
    int node = node0 + tid;
    if (node < N) rowptr[node] = beg + excl;
    cur[tid] = beg + excl;
    __syncthreads();
    for (int i = beg + tid; i < end; i += 256) {
        unsigned w = bucketData[i];
        int pos = atomicAdd(&cur[w >> 24], 1);
        sortedDst[pos] = (int)(w & 0xFFFFFFu);
    }
}

#define EDGE_FMA(g, al, A)                                                   \
    A[0] = fmaf(al, __uint_as_float(g.x << 16), A[0]);                       \
    A[1] = fmaf(al, __uint_as_float(g.x & 0xFFFF0000u), A[1]);               \
    A[2] = fmaf(al, __uint_as_float(g.y << 16), A[2]);                       \
    A[3] = fmaf(al, __uint_as_float(g.y & 0xFFFF0000u), A[3]);               \
    A[4] = fmaf(al, __uint_as_float(g.z << 16), A[4]);                       \
    A[5] = fmaf(al, __uint_as_float(g.z & 0xFFFF0000u), A[5]);               \
    A[6] = fmaf(al, __uint_as_float(g.w << 16), A[6]);                       \
    A[7] = fmaf(al, __uint_as_float(g.w & 0xFFFF0000u), A[7]);

// ---------------- Kernel 5: aggregate, 8 nodes/wave, 4-edge unroll ----------
__global__ __launch_bounds__(256) void gat_aggregate(
    const int* __restrict__ rowptr,
    const int* __restrict__ sortedDst,
    const float* __restrict__ s1, const float* __restrict__ s2,
    const unsigned short* __restrict__ hb, float* __restrict__ out, int N) {
    int tid = threadIdx.x;
    int node = blockIdx.x * 32 + (tid >> 3);
    if (node >= N) return;
    const int fo = (tid & 7) * 8;    // feature octet owned by this lane

    int beg = rowptr[node];
    int end = rowptr[node + 1];
    float s1s = s1[node];
    float as = s1s + s2[node];
    as = (as >= 0.f) ? as : SLOPE * as;
    as = expf(as);

    float accA[8], accB[8];
    {
        uint4 hv = *(const uint4*)&hb[(size_t)node * F + fo];
        accA[0] = as * __uint_as_float(hv.x << 16);
        accA[1] = as * __uint_as_float(hv.x & 0xFFFF0000u);
        accA[2] = as * __uint_as_float(hv.y << 16);
        accA[3] = as * __uint_as_float(hv.y & 0xFFFF0000u);
        accA[4] = as * __uint_as_float(hv.z << 16);
        accA[5] = as * __uint_as_float(hv.z & 0xFFFF0000u);
        accA[6] = as * __uint_as_float(hv.w << 16);
        accA[7] = as * __uint_as_float(hv.w & 0xFFFF0000u);
    }
#pragma unroll
    for (int i = 0; i < 8; ++i) accB[i] = 0.f;

    float dsum = as;
    int e = beg;
    // 4-edge unroll: 4 index loads + 4 s2 loads + 4 gathers in flight
    for (; e + 4 <= end; e += 4) {
        int d0 = sortedDst[e];
        int d1 = sortedDst[e + 1];
        int d2 = sortedDst[e + 2];
        int d3 = sortedDst[e + 3];
        float t0 = s1s + s2[d0];
        float t1 = s1s + s2[d1];
        float t2 = s1s + s2[d2];
        float t3 = s1s + s2[d3];
        uint4 g0 = *(const uint4*)&hb[(size_t)d0 * F + fo];
        uint4 g1 = *(const uint4*)&hb[(size_t)d1 * F + fo];
        uint4 g2 = *(const uint4*)&hb[(size_t)d2 * F + fo];
        uint4 g3 = *(const uint4*)&hb[(size_t)d3 * F + fo];
        t0 = (t0 >= 0.f) ? t0 : SLOPE * t0;
        t1 = (t1 >= 0.f) ? t1 : SLOPE * t1;
        t2 = (t2 >= 0.f) ? t2 : SLOPE * t2;
        t3 = (t3 >= 0.f) ? t3 : SLOPE * t3;
        float a0 = expf(t0);
        float a1 = expf(t1);
        float a2 = expf(t2);
        float a3 = expf(t3);
        dsum += (a0 + a1) + (a2 + a3);
        EDGE_FMA(g0, a0, accA);
        EDGE_FMA(g1, a1, accB);
        EDGE_FMA(g2, a2, accA);
        EDGE_FMA(g3, a3, accB);
    }
    // tail (0-3 edges)
    for (; e < end; ++e) {
        int d0 = sortedDst[e];
        float t0 = s1s + s2[d0];
        t0 = (t0 >= 0.f) ? t0 : SLOPE * t0;
        float a0 = expf(t0);
        dsum += a0;
        uint4 g0 = *(const uint4*)&hb[(size_t)d0 * F + fo];
        EDGE_FMA(g0, a0, accA);
    }

    float inv = 1.0f / dsum;
    float4 r0, r1;
    r0.x = (accA[0] + accB[0]) * inv;
    r0.y = (accA[1] + accB[1]) * inv;
    r0.z = (accA[2] + accB[2]) * inv;
    r0.w = (accA[3] + accB[3]) * inv;
    r1.x = (accA[4] + accB[4]) * inv;
    r1.y = (accA[5] + accB[5]) * inv;
    r1.z = (accA[6] + accB[6]) * inv;
    r1.w = (accA[7] + accB[7]) * inv;
    *(float4*)&out[(size_t)node * F + fo] = r0;
    *(float4*)&out[(size_t)node * F + fo + 4] = r1;
}

extern "C" void kernel_launch(void* const* d_in, const int* in_sizes, int n_in,
                              void* d_out, int out_size, void* d_ws, size_t ws_size,
                              hipStream_t stream) {
    const float* X = (const float*)d_in[0];
    const int* edge = (const int*)d_in[1];
    const float* W = (const float*)d_in[2];
    const float* a = (const float*)d_in[3];

    int N = in_sizes[0] / F;
    int E = in_sizes[1] / 2;
    int NB = (N + 255) >> NB_SHIFT;   // 256-node buckets (<= 512)

    const int* src = edge;
    const int* dst = edge + E;

    // ws: bucketData[E]u32 | hb[N*64]u16 | s1[N] | s2[N] |
    //     partialHist[128*512] | bucketBase[513] | bucketCursor[512] |
    //     rowptr[N+1] | sortedDst[E] | Wp[4096]u16 | w1[64] | w2[64]
    unsigned* bucketData = (unsigned*)d_ws;
    unsigned short* hb = (unsigned short*)(bucketData + E);
    float* s1 = (float*)(hb + (size_t)N * F);
    float* s2 = s1 + N;
    int* partialHist = (int*)(s2 + N);
    int* bucketBase = partialHist + HIST_BLOCKS * 512;
    int* bucketCursor = bucketBase + 513;
    int* rowptr = bucketCursor + 512;
    int* sortedDst = rowptr + (N + 1);
    unsigned short* Wp = (unsigned short*)(sortedDst + E);
    float* w1 = (float*)(Wp + 4096);
    float* w2 = w1 + 64;

    float* out = (float*)d_out;

    gat_prep<<<1, 256, 0, stream>>>(W, a, Wp, w1, w2);

    int gemmBlocks = (N + 63) / 64;
    gat_gemm_hist<<<gemmBlocks + HIST_BLOCKS, 256, 0, stream>>>(
        X, Wp, w1, w2, hb, s1, s2, N, src, partialHist, E, gemmBlocks);

    gat_scan0<<<1, 512, 0, stream>>>(partialHist, bucketBase, bucketCursor,
                                     rowptr + N, NB);

    int binBlocks = (E + BATCH - 1) / BATCH;
    gat_bin<<<binBlocks, 512, 0, stream>>>(src, dst, bucketCursor, bucketData, E);

    gat_bucket<<<NB, 256, 0, stream>>>(bucketBase, bucketData, rowptr,
                                       sortedDst, N);

    int aggBlocks = (N + 31) / 32;
    gat_aggregate<<<aggBlocks, 256, 0, stream>>>(rowptr, sortedDst,
                                                 s1, s2, hb, out, N);
}

// Round 18
// 92.848 us; speedup vs baseline: 1.3632x; 1.1304x over previous
//
#include <hip/hip_runtime.h>
#include <hip/hip_bf16.h>

#define F 64
#define SLOPE 0.2f
#define NB_SHIFT 8     // 256 nodes per coarse bucket
#define BATCH 4096     // edges per gat_bin block
#define SLAB 5120      // slab capacity per bucket (mean 4096, sigma ~64 -> +16σ)

typedef __attribute__((ext_vector_type(8))) short bf16x8;
typedef __attribute__((ext_vector_type(4))) float f32x4;

__device__ inline unsigned short f2bf(float f) {
    unsigned u = __float_as_uint(f);
    unsigned r = (u + 0x7FFFu + ((u >> 16) & 1u)) >> 16;
    return (unsigned short)r;
}

// ---------------- Kernel 0: prep Wp, w1/w2, slab cursors (1 block) ----------
__global__ __launch_bounds__(256) void gat_prep(
    const float* __restrict__ W, const float* __restrict__ a,
    unsigned short* __restrict__ Wp, float* __restrict__ w1,
    float* __restrict__ w2, int* __restrict__ bucketCursor) {
    int tid = threadIdx.x;
    // slab cursor init (512 entries; unused tail harmless)
    for (int i = tid; i < 512; i += 256) bucketCursor[i] = i * SLAB;

    if (tid < 64) {
        // B fragment f = cg*2 + kc; lane tid: col = cg*16 + (tid&15),
        // k = kc*32 + (tid>>4)*8 + j
#pragma unroll
        for (int f = 0; f < 8; ++f) {
            int cg = f >> 1, kc = f & 1;
            int col = cg * 16 + (tid & 15);
            unsigned short us[8];
#pragma unroll
            for (int j = 0; j < 8; ++j) {
                int k = kc * 32 + (tid >> 4) * 8 + j;
                us[j] = f2bf(W[k * F + col]);
            }
            uint4 pk;
            pk.x = us[0] | ((unsigned)us[1] << 16);
            pk.y = us[2] | ((unsigned)us[3] << 16);
            pk.z = us[4] | ((unsigned)us[5] << 16);
            pk.w = us[6] | ((unsigned)us[7] << 16);
            *(uint4*)&Wp[(f * 64 + tid) * 8] = pk;
        }
    } else if (tid < 128) {
        int k = tid - 64;
        float acc1 = 0.f, acc2 = 0.f;
#pragma unroll
        for (int n = 0; n < F; ++n) {
            float wv = W[k * F + n];
            acc1 = fmaf(wv, a[n], acc1);
            acc2 = fmaf(wv, a[F + n], acc2);
        }
        w1[k] = acc1;
        w2[k] = acc2;
    }
}

// ---------------- Kernel 1: MFMA gemm: h(bf16) = X @ W, exact s1/s2 ---------
__global__ __launch_bounds__(256) void gat_gemm_mfma(
    const float* __restrict__ X, const unsigned short* __restrict__ Wp,
    const float* __restrict__ w1, const float* __restrict__ w2,
    unsigned short* __restrict__ hb, float* __restrict__ s1,
    float* __restrict__ s2, int N) {
    int tid = threadIdx.x;
    int lane = tid & 63;
    int wv = tid >> 6;
    int rowBase = blockIdx.x * 64 + wv * 16;
    if (rowBase >= N) return;
    int lrow = lane & 15;
    int kg = lane >> 4;          // 0..3
    int row = rowBase + lrow;
    int rclamp = (row < N) ? row : (N - 1);

    const float* xp = &X[(size_t)rclamp * F + kg * 8];
    float4 u0 = *(const float4*)(xp + 0);
    float4 u1 = *(const float4*)(xp + 4);
    float4 u2 = *(const float4*)(xp + 32);
    float4 u3 = *(const float4*)(xp + 36);
    float xr[16] = {u0.x, u0.y, u0.z, u0.w, u1.x, u1.y, u1.z, u1.w,
                    u2.x, u2.y, u2.z, u2.w, u3.x, u3.y, u3.z, u3.w};

    bf16x8 a0, a1;
#pragma unroll
    for (int j = 0; j < 8; ++j) {
        a0[j] = (short)f2bf(xr[j]);
        a1[j] = (short)f2bf(xr[8 + j]);
    }

    bf16x8 bf0 = *(const bf16x8*)&Wp[(0 * 64 + lane) * 8];
    bf16x8 bf1 = *(const bf16x8*)&Wp[(1 * 64 + lane) * 8];
    bf16x8 bf2 = *(const bf16x8*)&Wp[(2 * 64 + lane) * 8];
    bf16x8 bf3 = *(const bf16x8*)&Wp[(3 * 64 + lane) * 8];
    bf16x8 bf4 = *(const bf16x8*)&Wp[(4 * 64 + lane) * 8];
    bf16x8 bf5 = *(const bf16x8*)&Wp[(5 * 64 + lane) * 8];
    bf16x8 bf6 = *(const bf16x8*)&Wp[(6 * 64 + lane) * 8];
    bf16x8 bf7 = *(const bf16x8*)&Wp[(7 * 64 + lane) * 8];

    f32x4 acc0 = {0.f, 0.f, 0.f, 0.f};
    f32x4 acc1v = {0.f, 0.f, 0.f, 0.f};
    f32x4 acc2v = {0.f, 0.f, 0.f, 0.f};
    f32x4 acc3 = {0.f, 0.f, 0.f, 0.f};
    acc0 = __builtin_amdgcn_mfma_f32_16x16x32_bf16(a0, bf0, acc0, 0, 0, 0);
    acc0 = __builtin_amdgcn_mfma_f32_16x16x32_bf16(a1, bf1, acc0, 0, 0, 0);
    acc1v = __builtin_amdgcn_mfma_f32_16x16x32_bf16(a0, bf2, acc1v, 0, 0, 0);
    acc1v = __builtin_amdgcn_mfma_f32_16x16x32_bf16(a1, bf3, acc1v, 0, 0, 0);
    acc2v = __builtin_amdgcn_mfma_f32_16x16x32_bf16(a0, bf4, acc2v, 0, 0, 0);
    acc2v = __builtin_amdgcn_mfma_f32_16x16x32_bf16(a1, bf5, acc2v, 0, 0, 0);
    acc3 = __builtin_amdgcn_mfma_f32_16x16x32_bf16(a0, bf6, acc3, 0, 0, 0);
    acc3 = __builtin_amdgcn_mfma_f32_16x16x32_bf16(a1, bf7, acc3, 0, 0, 0);

#pragma unroll
    for (int r = 0; r < 4; ++r) {
        int ro = rowBase + kg * 4 + r;
        if (ro < N) {
            size_t rb = (size_t)ro * F + lrow;
            hb[rb + 0] = f2bf(acc0[r]);
            hb[rb + 16] = f2bf(acc1v[r]);
            hb[rb + 32] = f2bf(acc2v[r]);
            hb[rb + 48] = f2bf(acc3[r]);
        }
    }

    float4 wa0 = *(const float4*)&w1[kg * 8];
    float4 wa1 = *(const float4*)&w1[kg * 8 + 4];
    float4 wa2 = *(const float4*)&w1[32 + kg * 8];
    float4 wa3 = *(const float4*)&w1[32 + kg * 8 + 4];
    float4 wb0 = *(const float4*)&w2[kg * 8];
    float4 wb1 = *(const float4*)&w2[kg * 8 + 4];
    float4 wb2 = *(const float4*)&w2[32 + kg * 8];
    float4 wb3 = *(const float4*)&w2[32 + kg * 8 + 4];
    float wv1[16] = {wa0.x, wa0.y, wa0.z, wa0.w, wa1.x, wa1.y, wa1.z, wa1.w,
                     wa2.x, wa2.y, wa2.z, wa2.w, wa3.x, wa3.y, wa3.z, wa3.w};
    float wv2[16] = {wb0.x, wb0.y, wb0.z, wb0.w, wb1.x, wb1.y, wb1.z, wb1.w,
                     wb2.x, wb2.y, wb2.z, wb2.w, wb3.x, wb3.y, wb3.z, wb3.w};
    float p = 0.f, q = 0.f;
#pragma unroll
    for (int j = 0; j < 16; ++j) {
        p = fmaf(xr[j], wv1[j], p);
        q = fmaf(xr[j], wv2[j], q);
    }
    p += __shfl_xor(p, 16, 64);
    p += __shfl_xor(p, 32, 64);
    q += __shfl_xor(q, 16, 64);
    q += __shfl_xor(q, 32, 64);
    if (lane < 16 && row < N) {
        s1[row] = p;
        s2[row] = q;
    }
}

// ---------------- Kernel 2: coarse radix partition into slabs ---------------
// bucketData element: (src & 255) << 24 | dst   (dst < 2^24); slab cursors
// pre-initialized to b*SLAB by gat_prep.
__global__ __launch_bounds__(512) void gat_bin(
    const int* __restrict__ src, const int* __restrict__ dst,
    int* __restrict__ bucketCursor, unsigned* __restrict__ bucketData, int E) {
    __shared__ int hist[512], excl[512], gbase[512], cur[512];
    __shared__ int wsum[8];
    __shared__ int2 staged[BATCH];
    int tid = threadIdx.x, lane = tid & 63, wid = tid >> 6;
    int base = blockIdx.x * BATCH;
    int n = E - base;
    if (n > BATCH) n = BATCH;

    hist[tid] = 0;
    __syncthreads();

    int se[8], de[8];
#pragma unroll
    for (int j = 0; j < 8; ++j) {
        int i = base + j * 512 + tid;
        se[j] = -1;
        de[j] = 0;
        if (i < E) {
            se[j] = src[i];
            de[j] = dst[i];
            atomicAdd(&hist[se[j] >> NB_SHIFT], 1);
        }
    }
    __syncthreads();
    int v = hist[tid];
    int x = v;
#pragma unroll
    for (int off = 1; off < 64; off <<= 1) {
        int y = __shfl_up(x, off, 64);
        if (lane >= off) x += y;
    }
    if (lane == 63) wsum[wid] = x;
    __syncthreads();
    int add = 0;
    for (int w = 0; w < 8; ++w)
        if (w < wid) add += wsum[w];
    int ex = add + x - v;
    excl[tid] = ex;
    cur[tid] = ex;
    __syncthreads();
#pragma unroll
    for (int j = 0; j < 8; ++j) {
        if (se[j] >= 0) {
            int b = se[j] >> NB_SHIFT;
            int pos = atomicAdd(&cur[b], 1);
            staged[pos] = make_int2(se[j], de[j]);
        }
    }
    if (v > 0)
        gbase[tid] = atomicAdd(&bucketCursor[tid], v);
    __syncthreads();
    for (int i = tid; i < n; i += 512) {
        int2 p = staged[i];
        int b = p.x >> NB_SHIFT;
        bucketData[gbase[b] + (i - excl[b])] =
            ((unsigned)(p.x & 255) << 24) | (unsigned)p.y;
    }
}

// ---------------- Kernel 3: bucket CSR + alpha precompute -------------------
// One block per bucket: counts, scan -> rowbeg/rowend, then scatter
// (dst, alpha) pairs into the bucket's sortedData slab. Alpha computed here
// (dense, high-TLP) so aggregate's chain is just pair-load -> gather -> FMA.
__global__ __launch_bounds__(256) void gat_bucket(
    const int* __restrict__ bucketCursor, const unsigned* __restrict__ bucketData,
    const float* __restrict__ s1, const float* __restrict__ s2,
    int* __restrict__ rowbeg, int* __restrict__ rowend,
    int2* __restrict__ sortedData, int N) {
    __shared__ int cnt[256], cur[256];
    __shared__ float s1l[256];
    __shared__ int wsum[4];
    int b = blockIdx.x;
    int tid = threadIdx.x, lane = tid & 63, wid = tid >> 6;
    int beg = b * SLAB;
    int end = bucketCursor[b];
    int node0 = b << NB_SHIFT;
    int node = node0 + tid;

    cnt[tid] = 0;
    s1l[tid] = (node < N) ? s1[node] : 0.f;
    __syncthreads();
    for (int i = beg + tid; i < end; i += 256)
        atomicAdd(&cnt[bucketData[i] >> 24], 1);
    __syncthreads();
    int v = cnt[tid];
    int x = v;
#pragma unroll
    for (int off = 1; off < 64; off <<= 1) {
        int y = __shfl_up(x, off, 64);
        if (lane >= off) x += y;
    }
    if (lane == 63) wsum[wid] = x;
    __syncthreads();
    int add = 0;
    for (int w = 0; w < 4; ++w)
        if (w < wid) add += wsum[w];
    int excl = add + x - v;
    if (node < N) {
        rowbeg[node] = beg + excl;
        rowend[node] = beg + excl + v;
    }
    cur[tid] = beg + excl;
    __syncthreads();
    for (int i = beg + tid; i < end; i += 256) {
        unsigned w = bucketData[i];
        int sloc = w >> 24;
        int d = (int)(w & 0xFFFFFFu);
        float t = s1l[sloc] + s2[d];
        t = (t >= 0.f) ? t : SLOPE * t;
        float al = expf(t);
        int pos = atomicAdd(&cur[sloc], 1);
        sortedData[pos] = make_int2(d, __float_as_int(al));
    }
}

#define EDGE_FMA(g, al, A)                                                   \
    A[0] = fmaf(al, __uint_as_float(g.x << 16), A[0]);                       \
    A[1] = fmaf(al, __uint_as_float(g.x & 0xFFFF0000u), A[1]);               \
    A[2] = fmaf(al, __uint_as_float(g.y << 16), A[2]);                       \
    A[3] = fmaf(al, __uint_as_float(g.y & 0xFFFF0000u), A[3]);               \
    A[4] = fmaf(al, __uint_as_float(g.z << 16), A[4]);                       \
    A[5] = fmaf(al, __uint_as_float(g.z & 0xFFFF0000u), A[5]);               \
    A[6] = fmaf(al, __uint_as_float(g.w << 16), A[6]);                       \
    A[7] = fmaf(al, __uint_as_float(g.w & 0xFFFF0000u), A[7]);

// ---------------- Kernel 4: aggregate, 8 nodes/wave, pair stream ------------
__global__ __launch_bounds__(256) void gat_aggregate(
    const int* __restrict__ rowbeg, const int* __restrict__ rowend,
    const int2* __restrict__ sortedData,
    const float* __restrict__ s1, const float* __restrict__ s2,
    const unsigned short* __restrict__ hb, float* __restrict__ out, int N) {
    int tid = threadIdx.x;
    int node = blockIdx.x * 32 + (tid >> 3);
    if (node >= N) return;
    const int fo = (tid & 7) * 8;    // feature octet owned by this lane

    int beg = rowbeg[node];
    int end = rowend[node];
    float as = s1[node] + s2[node];
    as = (as >= 0.f) ? as : SLOPE * as;
    as = expf(as);

    float accA[8], accB[8];
    {
        uint4 hv = *(const uint4*)&hb[(size_t)node * F + fo];
        accA[0] = as * __uint_as_float(hv.x << 16);
        accA[1] = as * __uint_as_float(hv.x & 0xFFFF0000u);
        accA[2] = as * __uint_as_float(hv.y << 16);
        accA[3] = as * __uint_as_float(hv.y & 0xFFFF0000u);
        accA[4] = as * __uint_as_float(hv.z << 16);
        accA[5] = as * __uint_as_float(hv.z & 0xFFFF0000u);
        accA[6] = as * __uint_as_float(hv.w << 16);
        accA[7] = as * __uint_as_float(hv.w & 0xFFFF0000u);
    }
#pragma unroll
    for (int i = 0; i < 8; ++i) accB[i] = 0.f;

    float dsum = as;
    int e = beg;
    for (; e + 4 <= end; e += 4) {
        int2 p0 = sortedData[e];
        int2 p1 = sortedData[e + 1];
        int2 p2 = sortedData[e + 2];
        int2 p3 = sortedData[e + 3];
        uint4 g0 = *(const uint4*)&hb[(size_t)p0.x * F + fo];
        uint4 g1 = *(const uint4*)&hb[(size_t)p1.x * F + fo];
        uint4 g2 = *(const uint4*)&hb[(size_t)p2.x * F + fo];
        uint4 g3 = *(const uint4*)&hb[(size_t)p3.x * F + fo];
        float a0 = __int_as_float(p0.y);
        float a1 = __int_as_float(p1.y);
        float a2 = __int_as_float(p2.y);
        float a3 = __int_as_float(p3.y);
        dsum += (a0 + a1) + (a2 + a3);
        EDGE_FMA(g0, a0, accA);
        EDGE_FMA(g1, a1, accB);
        EDGE_FMA(g2, a2, accA);
        EDGE_FMA(g3, a3, accB);
    }
    for (; e < end; ++e) {
        int2 p0 = sortedData[e];
        float a0 = __int_as_float(p0.y);
        dsum += a0;
        uint4 g0 = *(const uint4*)&hb[(size_t)p0.x * F + fo];
        EDGE_FMA(g0, a0, accA);
    }

    float inv = 1.0f / dsum;
    float4 r0, r1;
    r0.x = (accA[0] + accB[0]) * inv;
    r0.y = (accA[1] + accB[1]) * inv;
    r0.z = (accA[2] + accB[2]) * inv;
    r0.w = (accA[3] + accB[3]) * inv;
    r1.x = (accA[4] + accB[4]) * inv;
    r1.y = (accA[5] + accB[5]) * inv;
    r1.z = (accA[6] + accB[6]) * inv;
    r1.w = (accA[7] + accB[7]) * inv;
    *(float4*)&out[(size_t)node * F + fo] = r0;
    *(float4*)&out[(size_t)node * F + fo + 4] = r1;
}

extern "C" void kernel_launch(void* const* d_in, const int* in_sizes, int n_in,
                              void* d_out, int out_size, void* d_ws, size_t ws_size,
                              hipStream_t stream) {
    const float* X = (const float*)d_in[0];
    const int* edge = (const int*)d_in[1];
    const float* W = (const float*)d_in[2];
    const float* a = (const float*)d_in[3];

    int N = in_sizes[0] / F;
    int E = in_sizes[1] / 2;
    int NB = (N + 255) >> NB_SHIFT;   // 256-node buckets (<= 512)

    const int* src = edge;
    const int* dst = edge + E;

    // ws: bucketData[NB*SLAB]u32 | sortedData[NB*SLAB]int2 | hb[N*64]u16 |
    //     s1[N] | s2[N] | rowbeg[N] | rowend[N] | bucketCursor[512] |
    //     Wp[4096]u16 | w1[64] | w2[64]
    unsigned* bucketData = (unsigned*)d_ws;
    int2* sortedData = (int2*)(bucketData + (size_t)NB * SLAB);
    unsigned short* hb = (unsigned short*)(sortedData + (size_t)NB * SLAB);
    float* s1 = (float*)(hb + (size_t)N * F);
    float* s2 = s1 + N;
    int* rowbeg = (int*)(s2 + N);
    int* rowend = rowbeg + N;
    int* bucketCursor = rowend + N;
    unsigned short* Wp = (unsigned short*)(bucketCursor + 512);
    float* w1 = (float*)(Wp + 4096);
    float* w2 = w1 + 64;

    float* out = (float*)d_out;

    gat_prep<<<1, 256, 0, stream>>>(W, a, Wp, w1, w2, bucketCursor);

    int gemmBlocks = (N + 63) / 64;
    gat_gemm_mfma<<<gemmBlocks, 256, 0, stream>>>(X, Wp, w1, w2, hb, s1, s2, N);

    int binBlocks = (E + BATCH - 1) / BATCH;
    gat_bin<<<binBlocks, 512, 0, stream>>>(src, dst, bucketCursor, bucketData, E);

    gat_bucket<<<NB, 256, 0, stream>>>(bucketCursor, bucketData, s1, s2,
                                       rowbeg, rowend, sortedData, N);

    int aggBlocks = (N + 31) / 32;
    gat_aggregate<<<aggBlocks, 256, 0, stream>>>(rowbeg, rowend, sortedData,
                                                 s1, s2, hb, out, N);
}

// Round 19
// 87.484 us; speedup vs baseline: 1.4467x; 1.0613x over previous
//
#include <hip/hip_runtime.h>
#include <hip/hip_bf16.h>

#define F 64
#define SLOPE 0.2f
#define NB_SHIFT 8     // 256 nodes per coarse bucket
#define BATCH 4096     // edges per bin block-part
#define SLAB 5120      // slab capacity per bucket (mean 4096, sigma ~64 -> +16σ)

typedef __attribute__((ext_vector_type(8))) short bf16x8;
typedef __attribute__((ext_vector_type(4))) float f32x4;

__device__ inline unsigned short f2bf(float f) {
    unsigned u = __float_as_uint(f);
    unsigned r = (u + 0x7FFFu + ((u >> 16) & 1u)) >> 16;
    return (unsigned short)r;
}

// ---------------- Kernel 0: prep Wp, w1/w2, slab cursors (1 block) ----------
__global__ __launch_bounds__(256) void gat_prep(
    const float* __restrict__ W, const float* __restrict__ a,
    unsigned short* __restrict__ Wp, float* __restrict__ w1,
    float* __restrict__ w2, int* __restrict__ bucketCursor) {
    int tid = threadIdx.x;
    for (int i = tid; i < 512; i += 256) bucketCursor[i] = i * SLAB;

    if (tid < 64) {
#pragma unroll
        for (int f = 0; f < 8; ++f) {
            int cg = f >> 1, kc = f & 1;
            int col = cg * 16 + (tid & 15);
            unsigned short us[8];
#pragma unroll
            for (int j = 0; j < 8; ++j) {
                int k = kc * 32 + (tid >> 4) * 8 + j;
                us[j] = f2bf(W[k * F + col]);
            }
            uint4 pk;
            pk.x = us[0] | ((unsigned)us[1] << 16);
            pk.y = us[2] | ((unsigned)us[3] << 16);
            pk.z = us[4] | ((unsigned)us[5] << 16);
            pk.w = us[6] | ((unsigned)us[7] << 16);
            *(uint4*)&Wp[(f * 64 + tid) * 8] = pk;
        }
    } else if (tid < 128) {
        int k = tid - 64;
        float acc1 = 0.f, acc2 = 0.f;
#pragma unroll
        for (int n = 0; n < F; ++n) {
            float wv = W[k * F + n];
            acc1 = fmaf(wv, a[n], acc1);
            acc2 = fmaf(wv, a[F + n], acc2);
        }
        w1[k] = acc1;
        w2[k] = acc2;
    }
}

// ---------------- Kernel 1: fused [MFMA gemm (512thr)] ∥ [bin partition] ----
// Blocks [0, gemmBlocks): gemm, 128 rows/block, 8 waves, no LDS use.
// Blocks [gemmBlocks, +binBlocks): slab radix partition (40 KB LDS).
__global__ __launch_bounds__(512) void gat_gemm_bin(
    const float* __restrict__ X, const unsigned short* __restrict__ Wp,
    const float* __restrict__ w1, const float* __restrict__ w2,
    unsigned short* __restrict__ hb, float* __restrict__ s1,
    float* __restrict__ s2, int N,
    const int* __restrict__ src, const int* __restrict__ dst,
    int* __restrict__ bucketCursor, unsigned* __restrict__ bucketData, int E,
    int gemmBlocks) {
    __shared__ int hist[512], excl[512], gbase[512], cur[512];
    __shared__ int wsum[8];
    __shared__ int2 staged[BATCH];

    int tid = threadIdx.x;
    int lane = tid & 63, wid = tid >> 6;

    if ((int)blockIdx.x >= gemmBlocks) {
        // ---------------- bin part ----------------
        int base = (blockIdx.x - gemmBlocks) * BATCH;
        int n = E - base;
        if (n > BATCH) n = BATCH;

        hist[tid] = 0;
        __syncthreads();

        int se[8], de[8];
#pragma unroll
        for (int j = 0; j < 8; ++j) {
            int i = base + j * 512 + tid;
            se[j] = -1;
            de[j] = 0;
            if (i < E) {
                se[j] = src[i];
                de[j] = dst[i];
                atomicAdd(&hist[se[j] >> NB_SHIFT], 1);
            }
        }
        __syncthreads();
        int v = hist[tid];
        int x = v;
#pragma unroll
        for (int off = 1; off < 64; off <<= 1) {
            int y = __shfl_up(x, off, 64);
            if (lane >= off) x += y;
        }
        if (lane == 63) wsum[wid] = x;
        __syncthreads();
        int add = 0;
        for (int w = 0; w < 8; ++w)
            if (w < wid) add += wsum[w];
        int ex = add + x - v;
        excl[tid] = ex;
        cur[tid] = ex;
        __syncthreads();
#pragma unroll
        for (int j = 0; j < 8; ++j) {
            if (se[j] >= 0) {
                int b = se[j] >> NB_SHIFT;
                int pos = atomicAdd(&cur[b], 1);
                staged[pos] = make_int2(se[j], de[j]);
            }
        }
        if (v > 0)
            gbase[tid] = atomicAdd(&bucketCursor[tid], v);
        __syncthreads();
        for (int i = tid; i < n; i += 512) {
            int2 p = staged[i];
            int b = p.x >> NB_SHIFT;
            bucketData[gbase[b] + (i - excl[b])] =
                ((unsigned)(p.x & 255) << 24) | (unsigned)p.y;
        }
        return;
    }

    // ---------------- gemm part (one wave per 16-row tile) ----------------
    int rowBase = blockIdx.x * 128 + wid * 16;
    if (rowBase >= N) return;
    int lrow = lane & 15;
    int kg = lane >> 4;          // 0..3
    int row = rowBase + lrow;
    int rclamp = (row < N) ? row : (N - 1);

    const float* xp = &X[(size_t)rclamp * F + kg * 8];
    float4 u0 = *(const float4*)(xp + 0);
    float4 u1 = *(const float4*)(xp + 4);
    float4 u2 = *(const float4*)(xp + 32);
    float4 u3 = *(const float4*)(xp + 36);
    float xr[16] = {u0.x, u0.y, u0.z, u0.w, u1.x, u1.y, u1.z, u1.w,
                    u2.x, u2.y, u2.z, u2.w, u3.x, u3.y, u3.z, u3.w};

    bf16x8 a0, a1;
#pragma unroll
    for (int j = 0; j < 8; ++j) {
        a0[j] = (short)f2bf(xr[j]);
        a1[j] = (short)f2bf(xr[8 + j]);
    }

    bf16x8 bf0 = *(const bf16x8*)&Wp[(0 * 64 + lane) * 8];
    bf16x8 bf1 = *(const bf16x8*)&Wp[(1 * 64 + lane) * 8];
    bf16x8 bf2 = *(const bf16x8*)&Wp[(2 * 64 + lane) * 8];
    bf16x8 bf3 = *(const bf16x8*)&Wp[(3 * 64 + lane) * 8];
    bf16x8 bf4 = *(const bf16x8*)&Wp[(4 * 64 + lane) * 8];
    bf16x8 bf5 = *(const bf16x8*)&Wp[(5 * 64 + lane) * 8];
    bf16x8 bf6 = *(const bf16x8*)&Wp[(6 * 64 + lane) * 8];
    bf16x8 bf7 = *(const bf16x8*)&Wp[(7 * 64 + lane) * 8];

    f32x4 acc0 = {0.f, 0.f, 0.f, 0.f};
    f32x4 acc1v = {0.f, 0.f, 0.f, 0.f};
    f32x4 acc2v = {0.f, 0.f, 0.f, 0.f};
    f32x4 acc3 = {0.f, 0.f, 0.f, 0.f};
    acc0 = __builtin_amdgcn_mfma_f32_16x16x32_bf16(a0, bf0, acc0, 0, 0, 0);
    acc0 = __builtin_amdgcn_mfma_f32_16x16x32_bf16(a1, bf1, acc0, 0, 0, 0);
    acc1v = __builtin_amdgcn_mfma_f32_16x16x32_bf16(a0, bf2, acc1v, 0, 0, 0);
    acc1v = __builtin_amdgcn_mfma_f32_16x16x32_bf16(a1, bf3, acc1v, 0, 0, 0);
    acc2v = __builtin_amdgcn_mfma_f32_16x16x32_bf16(a0, bf4, acc2v, 0, 0, 0);
    acc2v = __builtin_amdgcn_mfma_f32_16x16x32_bf16(a1, bf5, acc2v, 0, 0, 0);
    acc3 = __builtin_amdgcn_mfma_f32_16x16x32_bf16(a0, bf6, acc3, 0, 0, 0);
    acc3 = __builtin_amdgcn_mfma_f32_16x16x32_bf16(a1, bf7, acc3, 0, 0, 0);

#pragma unroll
    for (int r = 0; r < 4; ++r) {
        int ro = rowBase + kg * 4 + r;
        if (ro < N) {
            size_t rb = (size_t)ro * F + lrow;
            hb[rb + 0] = f2bf(acc0[r]);
            hb[rb + 16] = f2bf(acc1v[r]);
            hb[rb + 32] = f2bf(acc2v[r]);
            hb[rb + 48] = f2bf(acc3[r]);
        }
    }

    float4 wa0 = *(const float4*)&w1[kg * 8];
    float4 wa1 = *(const float4*)&w1[kg * 8 + 4];
    float4 wa2 = *(const float4*)&w1[32 + kg * 8];
    float4 wa3 = *(const float4*)&w1[32 + kg * 8 + 4];
    float4 wb0 = *(const float4*)&w2[kg * 8];
    float4 wb1 = *(const float4*)&w2[kg * 8 + 4];
    float4 wb2 = *(const float4*)&w2[32 + kg * 8];
    float4 wb3 = *(const float4*)&w2[32 + kg * 8 + 4];
    float wv1[16] = {wa0.x, wa0.y, wa0.z, wa0.w, wa1.x, wa1.y, wa1.z, wa1.w,
                     wa2.x, wa2.y, wa2.z, wa2.w, wa3.x, wa3.y, wa3.z, wa3.w};
    float wv2[16] = {wb0.x, wb0.y, wb0.z, wb0.w, wb1.x, wb1.y, wb1.z, wb1.w,
                     wb2.x, wb2.y, wb2.z, wb2.w, wb3.x, wb3.y, wb3.z, wb3.w};
    float p = 0.f, q = 0.f;
#pragma unroll
    for (int j = 0; j < 16; ++j) {
        p = fmaf(xr[j], wv1[j], p);
        q = fmaf(xr[j], wv2[j], q);
    }
    p += __shfl_xor(p, 16, 64);
    p += __shfl_xor(p, 32, 64);
    q += __shfl_xor(q, 16, 64);
    q += __shfl_xor(q, 32, 64);
    if (lane < 16 && row < N) {
        s1[row] = p;
        s2[row] = q;
    }
}

// ---------------- Kernel 2: bucket CSR + alpha precompute -------------------
__global__ __launch_bounds__(256) void gat_bucket(
    const int* __restrict__ bucketCursor, const unsigned* __restrict__ bucketData,
    const float* __restrict__ s1, const float* __restrict__ s2,
    int* __restrict__ rowbeg, int* __restrict__ rowend,
    int2* __restrict__ sortedData, int N) {
    __shared__ int cnt[256], cur[256];
    __shared__ float s1l[256];
    __shared__ int wsum[4];
    int b = blockIdx.x;
    int tid = threadIdx.x, lane = tid & 63, wid = tid >> 6;
    int beg = b * SLAB;
    int end = bucketCursor[b];
    int node0 = b << NB_SHIFT;
    int node = node0 + tid;

    cnt[tid] = 0;
    s1l[tid] = (node < N) ? s1[node] : 0.f;
    __syncthreads();
    for (int i = beg + tid; i < end; i += 256)
        atomicAdd(&cnt[bucketData[i] >> 24], 1);
    __syncthreads();
    int v = cnt[tid];
    int x = v;
#pragma unroll
    for (int off = 1; off < 64; off <<= 1) {
        int y = __shfl_up(x, off, 64);
        if (lane >= off) x += y;
    }
    if (lane == 63) wsum[wid] = x;
    __syncthreads();
    int add = 0;
    for (int w = 0; w < 4; ++w)
        if (w < wid) add += wsum[w];
    int excl = add + x - v;
    if (node < N) {
        rowbeg[node] = beg + excl;
        rowend[node] = beg + excl + v;
    }
    cur[tid] = beg + excl;
    __syncthreads();
    for (int i = beg + tid; i < end; i += 256) {
        unsigned w = bucketData[i];
        int sloc = w >> 24;
        int d = (int)(w & 0xFFFFFFu);
        float t = s1l[sloc] + s2[d];
        t = (t >= 0.f) ? t : SLOPE * t;
        float al = expf(t);
        int pos = atomicAdd(&cur[sloc], 1);
        sortedData[pos] = make_int2(d, __float_as_int(al));
    }
}

#define EDGE_FMA(g, al, A)                                                   \
    A[0] = fmaf(al, __uint_as_float(g.x << 16), A[0]);                       \
    A[1] = fmaf(al, __uint_as_float(g.x & 0xFFFF0000u), A[1]);               \
    A[2] = fmaf(al, __uint_as_float(g.y << 16), A[2]);                       \
    A[3] = fmaf(al, __uint_as_float(g.y & 0xFFFF0000u), A[3]);               \
    A[4] = fmaf(al, __uint_as_float(g.z << 16), A[4]);                       \
    A[5] = fmaf(al, __uint_as_float(g.z & 0xFFFF0000u), A[5]);               \
    A[6] = fmaf(al, __uint_as_float(g.w << 16), A[6]);                       \
    A[7] = fmaf(al, __uint_as_float(g.w & 0xFFFF0000u), A[7]);

// ---------------- Kernel 3: aggregate, 8 nodes/wave, pair stream ------------
__global__ __launch_bounds__(256) void gat_aggregate(
    const int* __restrict__ rowbeg, const int* __restrict__ rowend,
    const int2* __restrict__ sortedData,
    const float* __restrict__ s1, const float* __restrict__ s2,
    const unsigned short* __restrict__ hb, float* __restrict__ out, int N) {
    int tid = threadIdx.x;
    int node = blockIdx.x * 32 + (tid >> 3);
    if (node >= N) return;
    const int fo = (tid & 7) * 8;

    int beg = rowbeg[node];
    int end = rowend[node];
    float as = s1[node] + s2[node];
    as = (as >= 0.f) ? as : SLOPE * as;
    as = expf(as);

    float accA[8], accB[8];
    {
        uint4 hv = *(const uint4*)&hb[(size_t)node * F + fo];
        accA[0] = as * __uint_as_float(hv.x << 16);
        accA[1] = as * __uint_as_float(hv.x & 0xFFFF0000u);
        accA[2] = as * __uint_as_float(hv.y << 16);
        accA[3] = as * __uint_as_float(hv.y & 0xFFFF0000u);
        accA[4] = as * __uint_as_float(hv.z << 16);
        accA[5] = as * __uint_as_float(hv.z & 0xFFFF0000u);
        accA[6] = as * __uint_as_float(hv.w << 16);
        accA[7] = as * __uint_as_float(hv.w & 0xFFFF0000u);
    }
#pragma unroll
    for (int i = 0; i < 8; ++i) accB[i] = 0.f;

    float dsum = as;
    int e = beg;
    for (; e + 4 <= end; e += 4) {
        int2 p0 = sortedData[e];
        int2 p1 = sortedData[e + 1];
        int2 p2 = sortedData[e + 2];
        int2 p3 = sortedData[e + 3];
        uint4 g0 = *(const uint4*)&hb[(size_t)p0.x * F + fo];
        uint4 g1 = *(const uint4*)&hb[(size_t)p1.x * F + fo];
        uint4 g2 = *(const uint4*)&hb[(size_t)p2.x * F + fo];
        uint4 g3 = *(const uint4*)&hb[(size_t)p3.x * F + fo];
        float a0 = __int_as_float(p0.y);
        float a1 = __int_as_float(p1.y);
        float a2 = __int_as_float(p2.y);
        float a3 = __int_as_float(p3.y);
        dsum += (a0 + a1) + (a2 + a3);
        EDGE_FMA(g0, a0, accA);
        EDGE_FMA(g1, a1, accB);
        EDGE_FMA(g2, a2, accA);
        EDGE_FMA(g3, a3, accB);
    }
    for (; e < end; ++e) {
        int2 p0 = sortedData[e];
        float a0 = __int_as_float(p0.y);
        dsum += a0;
        uint4 g0 = *(const uint4*)&hb[(size_t)p0.x * F + fo];
        EDGE_FMA(g0, a0, accA);
    }

    float inv = 1.0f / dsum;
    float4 r0, r1;
    r0.x = (accA[0] + accB[0]) * inv;
    r0.y = (accA[1] + accB[1]) * inv;
    r0.z = (accA[2] + accB[2]) * inv;
    r0.w = (accA[3] + accB[3]) * inv;
    r1.x = (accA[4] + accB[4]) * inv;
    r1.y = (accA[5] + accB[5]) * inv;
    r1.z = (accA[6] + accB[6]) * inv;
    r1.w = (accA[7] + accB[7]) * inv;
    *(float4*)&out[(size_t)node * F + fo] = r0;
    *(float4*)&out[(size_t)node * F + fo + 4] = r1;
}

extern "C" void kernel_launch(void* const* d_in, const int* in_sizes, int n_in,
                              void* d_out, int out_size, void* d_ws, size_t ws_size,
                              hipStream_t stream) {
    const float* X = (const float*)d_in[0];
    const int* edge = (const int*)d_in[1];
    const float* W = (const float*)d_in[2];
    const float* a = (const float*)d_in[3];

    int N = in_sizes[0] / F;
    int E = in_sizes[1] / 2;
    int NB = (N + 255) >> NB_SHIFT;   // 256-node buckets (<= 512)

    const int* src = edge;
    const int* dst = edge + E;

    // ws: bucketData[NB*SLAB]u32 | sortedData[NB*SLAB]int2 | hb[N*64]u16 |
    //     s1[N] | s2[N] | rowbeg[N] | rowend[N] | bucketCursor[512] |
    //     Wp[4096]u16 | w1[64] | w2[64]
    unsigned* bucketData = (unsigned*)d_ws;
    int2* sortedData = (int2*)(bucketData + (size_t)NB * SLAB);
    unsigned short* hb = (unsigned short*)(sortedData + (size_t)NB * SLAB);
    float* s1 = (float*)(hb + (size_t)N * F);
    float* s2 = s1 + N;
    int* rowbeg = (int*)(s2 + N);
    int* rowend = rowbeg + N;
    int* bucketCursor = rowend + N;
    unsigned short* Wp = (unsigned short*)(bucketCursor + 512);
    float* w1 = (float*)(Wp + 4096);
    float* w2 = w1 + 64;

    float* out = (float*)d_out;

    gat_prep<<<1, 256, 0, stream>>>(W, a, Wp, w1, w2, bucketCursor);

    int gemmBlocks = (N + 127) / 128;
    int binBlocks = (E + BATCH - 1) / BATCH;
    gat_gemm_bin<<<gemmBlocks + binBlocks, 512, 0, stream>>>(
        X, Wp, w1, w2, hb, s1, s2, N, src, dst, bucketCursor, bucketData, E,
        gemmBlocks);

    gat_bucket<<<NB, 256, 0, stream>>>(bucketCursor, bucketData, s1, s2,
                                       rowbeg, rowend, sortedData, N);

    int aggBlocks = (N + 31) / 32;
    gat_aggregate<<<aggBlocks, 256, 0, stream>>>(rowbeg, rowend, sortedData,
                                                 s1, s2, hb, out, N);
}